// Round 1
// baseline (53512.360 us; speedup 1.0000x reference)
//
#include <hip/hip_runtime.h>
#include <hip/hip_bf16.h>
#include <math.h>

// Problem constants
#define BATCH 1024
#define TT    256
#define DD    256
#define HH    768
#define LL    6
#define KCONV 10
#define CHW   128
#define GDIM  3084     // 4*H + 2*L
#define KPACK 1024     // D + H

// GEMM tile config
#define BM 64
#define BN 64
#define BK 32

__device__ __forceinline__ float sigf(float v) { return 1.0f / (1.0f + expf(-v)); }

// ---------------------------------------------------------------------------
// Pack combined weight matrix Wp[GDIM][1024] = [kernel_w[:, :256] | rec_w[:, :768]]
// tcoef[j] = kernel_w[j, 256] + rec_w[j, 768]   (both multiply time t)
// bias[j]  = kernel_b[j] + rec_b[j]
// ---------------------------------------------------------------------------
__global__ __launch_bounds__(256) void prep_kernel(
    const float* __restrict__ kw, const float* __restrict__ kb,
    const float* __restrict__ rw, const float* __restrict__ rb,
    float* __restrict__ Wp, float* __restrict__ tcoef, float* __restrict__ bias)
{
    int j = blockIdx.x;
    int tid = threadIdx.x;
    // x part: d = 0..255
    Wp[j * KPACK + tid] = kw[j * (DD + 1) + tid];
    // h part: m = 0..767
    for (int m = tid; m < HH; m += 256)
        Wp[j * KPACK + DD + m] = rw[j * (HH + 1) + m];
    if (tid == 0) {
        tcoef[j] = kw[j * (DD + 1) + DD] + rw[j * (HH + 1) + HH];
        bias[j]  = kb[j] + rb[j];
    }
}

// ---------------------------------------------------------------------------
// NT GEMM: C[M,N] = epi( A[M,K] * W[N,K]^T + bias )
// MODE 0: A is split-source (x slice at step t | h), epilogue += bias + time*tcoef
// MODE 1: plain + bias
// MODE 2: + bias, relu
// MODE 3: + bias, sigmoid
// ---------------------------------------------------------------------------
template <int MODE>
__global__ __launch_bounds__(256) void gemm_nt(
    const float* __restrict__ A, int lda,
    const float* __restrict__ xsrc, const float* __restrict__ hsrc, int tstep,
    const float* __restrict__ W, int ldw,
    const float* __restrict__ bias, const float* __restrict__ tcoef,
    const float* __restrict__ timep,
    float* __restrict__ C, int ldc, int M, int N, int Kdim)
{
    __shared__ float As[BK][BM + 4];
    __shared__ float Ws[BK][BN + 4];
    const int tid = threadIdx.x;
    const int bm = blockIdx.y * BM;
    const int bn = blockIdx.x * BN;
    const int tx = tid & 15;   // N direction
    const int ty = tid >> 4;   // M direction

    float acc[4][4];
#pragma unroll
    for (int i = 0; i < 4; ++i)
#pragma unroll
        for (int j = 0; j < 4; ++j) acc[i][j] = 0.0f;

    for (int k0 = 0; k0 < Kdim; k0 += BK) {
        // stage A tile (k-major in LDS)
#pragma unroll
        for (int i = 0; i < (BM * BK) / 256; ++i) {
            int linear = tid + i * 256;
            int r  = linear >> 5;    // 0..63 row within tile
            int kk = linear & 31;
            int gk = k0 + kk;
            int grow = bm + r;
            float v;
            if (MODE == 0) {
                v = (gk < DD) ? xsrc[grow * (TT * DD) + tstep * DD + gk]
                              : hsrc[grow * HH + (gk - DD)];
            } else {
                v = A[grow * lda + gk];
            }
            As[kk][r] = v;
        }
        // stage W tile
#pragma unroll
        for (int i = 0; i < (BN * BK) / 256; ++i) {
            int linear = tid + i * 256;
            int r  = linear >> 5;
            int kk = linear & 31;
            int gk = k0 + kk;
            int gcol = bn + r;
            Ws[kk][r] = (gcol < N) ? W[gcol * ldw + gk] : 0.0f;
        }
        __syncthreads();

#pragma unroll
        for (int kk = 0; kk < BK; ++kk) {
            float4 a4 = *(const float4*)&As[kk][ty * 4];
            float4 b4 = *(const float4*)&Ws[kk][tx * 4];
            float av[4] = {a4.x, a4.y, a4.z, a4.w};
            float bv[4] = {b4.x, b4.y, b4.z, b4.w};
#pragma unroll
            for (int i = 0; i < 4; ++i)
#pragma unroll
                for (int j = 0; j < 4; ++j)
                    acc[i][j] = fmaf(av[i], bv[j], acc[i][j]);
        }
        __syncthreads();
    }

    // epilogue
#pragma unroll
    for (int i = 0; i < 4; ++i) {
        int row = bm + ty * 4 + i;
        float tval = 0.0f;
        if (MODE == 0) tval = timep[row * TT + tstep];
#pragma unroll
        for (int j = 0; j < 4; ++j) {
            int col = bn + tx * 4 + j;
            if (col < N) {
                float v = acc[i][j] + bias[col];
                if (MODE == 0) v += tval * tcoef[col];
                if (MODE == 2) v = fmaxf(v, 0.0f);
                if (MODE == 3) v = sigf(v);
                C[row * ldc + col] = v;
            }
        }
    }
}

// ---------------------------------------------------------------------------
// Cell update: gates, c/h update, distance, sliding window write.
// One block per batch row, 256 threads, 3 channels per thread.
// ---------------------------------------------------------------------------
__global__ __launch_bounds__(256) void cell_kernel(
    const float* __restrict__ g,     // [B, GDIM]
    float* __restrict__ cbuf,        // [B, H]
    float* __restrict__ hbuf,        // [B, H]
    float* __restrict__ hwin,        // [KCONV, B, H]
    float* __restrict__ dist_out,    // [T, B]  (points into d_out)
    int tstep)
{
    int b = blockIdx.x;
    const float* gr = g + (size_t)b * GDIM;

    // softmax + cumsum over the 2L master gates (redundant in every thread)
    float fv[LL], iv[LL];
    float mf = -1e30f, mi = -1e30f;
#pragma unroll
    for (int l = 0; l < LL; ++l) {
        fv[l] = gr[l];        mf = fmaxf(mf, fv[l]);
        iv[l] = gr[LL + l];   mi = fmaxf(mi, iv[l]);
    }
    float sf = 0.0f, si = 0.0f;
#pragma unroll
    for (int l = 0; l < LL; ++l) {
        fv[l] = expf(fv[l] - mf); sf += fv[l];
        iv[l] = expf(iv[l] - mi); si += iv[l];
    }
    float fm[LL], im[LL];
    float run = 0.0f;
#pragma unroll
    for (int l = 0; l < LL; ++l) { run += fv[l] / sf; fm[l] = run; }
    run = 0.0f;
#pragma unroll
    for (int l = LL - 1; l >= 0; --l) { run += iv[l] / si; im[l] = run; }
    float dist = 1.0f - (fm[0] + fm[1] + fm[2] + fm[3] + fm[4] + fm[5]) * (1.0f / 6.0f);

    int slot = tstep % KCONV;
    float* hw = hwin + (size_t)slot * BATCH * HH + (size_t)b * HH;

#pragma unroll
    for (int j = 0; j < 3; ++j) {
        int e = threadIdx.x + j * 256;   // 0..767 = l*128 + ch
        int l = e >> 7;
        float fg = sigf(gr[2 * LL + e]);
        float ig = sigf(gr[2 * LL + HH + e]);
        float og = sigf(gr[2 * LL + 2 * HH + e]);
        float ci = tanhf(gr[2 * LL + 3 * HH + e]);
        float cl = cbuf[(size_t)b * HH + e];
        float fmv = fm[l], imv = im[l];
        float ov = fmv * imv;
        float cn = ov * (fg * cl + ig * ci) + (fmv - ov) * cl + (imv - ov) * ci;
        float hn = og * tanhf(cn);
        cbuf[(size_t)b * HH + e] = cn;
        hbuf[(size_t)b * HH + e] = hn;
        hw[e] = hn;
    }
    if (threadIdx.x == 0) dist_out[(size_t)tstep * BATCH + b] = dist;
}

// ---------------------------------------------------------------------------
// local_dis = softmax(cumsum(last-K distances))   -> ld[B, KCONV]
// ---------------------------------------------------------------------------
__global__ __launch_bounds__(256) void window_kernel(
    const float* __restrict__ dist_out, float* __restrict__ ld)
{
    int b = blockIdx.x * blockDim.x + threadIdx.x;
    if (b >= BATCH) return;
    float w[KCONV];
    float run = 0.0f, m = -1e30f;
#pragma unroll
    for (int k = 0; k < KCONV; ++k) {
        run += dist_out[(size_t)(TT - KCONV + k) * BATCH + b];
        w[k] = run;
        m = fmaxf(m, run);
    }
    float s = 0.0f;
#pragma unroll
    for (int k = 0; k < KCONV; ++k) { w[k] = expf(w[k] - m); s += w[k]; }
    float inv = 1.0f / s;
#pragma unroll
    for (int k = 0; k < KCONV; ++k) ld[b * KCONV + k] = w[k] * inv;
}

// ---------------------------------------------------------------------------
// Lh[b, e*KCONV + k] = hwin[slot(k)][b][e] * ld[b,k];  mh[b,e] = mean_k Lh
// ---------------------------------------------------------------------------
__global__ __launch_bounds__(256) void localh_kernel(
    const float* __restrict__ hwin, const float* __restrict__ ld,
    float* __restrict__ Lh, float* __restrict__ mh)
{
    int idx = blockIdx.x * 256 + threadIdx.x;     // 0 .. B*H-1
    int b = idx / HH;
    int e = idx - b * HH;
    float lv[KCONV];
#pragma unroll
    for (int k = 0; k < KCONV; ++k) lv[k] = ld[b * KCONV + k];
    float sum = 0.0f;
#pragma unroll
    for (int k = 0; k < KCONV; ++k) {
        int slot = (TT - KCONV + k) % KCONV;
        float v = hwin[(size_t)slot * BATCH * HH + (size_t)b * HH + e] * lv[k];
        Lh[(size_t)b * (HH * KCONV) + e * KCONV + k] = v;
        sum += v;
    }
    mh[idx] = sum * (1.0f / KCONV);
}

// ---------------------------------------------------------------------------
// output[b] = sigmoid( sum_e (theme*conv + h_last)[b,e] * out_w[e] + out_b )
// ---------------------------------------------------------------------------
__global__ __launch_bounds__(256) void out_kernel(
    const float* __restrict__ theme, const float* __restrict__ conv,
    const float* __restrict__ hbuf, const float* __restrict__ out_w,
    const float* __restrict__ out_b, float* __restrict__ out)
{
    __shared__ float red[256];
    int b = blockIdx.x;
    float p = 0.0f;
    for (int e = threadIdx.x; e < HH; e += 256)
        p += (theme[(size_t)b * HH + e] * conv[(size_t)b * HH + e] + hbuf[(size_t)b * HH + e]) * out_w[e];
    red[threadIdx.x] = p;
    __syncthreads();
    for (int s = 128; s > 0; s >>= 1) {
        if (threadIdx.x < s) red[threadIdx.x] += red[threadIdx.x + s];
        __syncthreads();
    }
    if (threadIdx.x == 0) out[b] = sigf(red[0] + out_b[0]);
}

// ---------------------------------------------------------------------------
extern "C" void kernel_launch(void* const* d_in, const int* in_sizes, int n_in,
                              void* d_out, int out_size, void* d_ws, size_t ws_size,
                              hipStream_t stream)
{
    const float* x       = (const float*)d_in[0];   // [B,T,D]
    const float* timep   = (const float*)d_in[1];   // [B,T]
    const float* kw      = (const float*)d_in[2];   // [GDIM, D+1]
    const float* kb      = (const float*)d_in[3];   // [GDIM]
    const float* rw      = (const float*)d_in[4];   // [GDIM, H+1]
    const float* rb      = (const float*)d_in[5];   // [GDIM]
    const float* scale_w = (const float*)d_in[6];   // [128, 768]
    const float* scale_b = (const float*)d_in[7];   // [128]
    const float* resc_w  = (const float*)d_in[8];   // [768, 128]
    const float* resc_b  = (const float*)d_in[9];   // [768]
    const float* conv_w  = (const float*)d_in[10];  // [768, 768, 10]
    const float* conv_b  = (const float*)d_in[11];  // [768]
    const float* out_w   = (const float*)d_in[12];  // [1, 768]
    const float* out_b   = (const float*)d_in[13];  // [1]

    float* outp  = (float*)d_out;       // [B]
    float* distp = outp + BATCH;        // [T, B]

    // workspace layout (floats)
    float* ws = (float*)d_ws;
    float* Wp     = ws;                    // GDIM*1024
    float* tcoef  = Wp + (size_t)GDIM * KPACK;         // GDIM
    float* biasb  = tcoef + GDIM;                      // GDIM
    float* g      = biasb + GDIM;                      // B*GDIM
    float* hbuf   = g + (size_t)BATCH * GDIM;          // B*H
    float* cbuf   = hbuf + (size_t)BATCH * HH;         // B*H
    float* hwin   = cbuf + (size_t)BATCH * HH;         // KCONV*B*H
    float* ld     = hwin + (size_t)KCONV * BATCH * HH; // B*KCONV
    float* Lh     = ld + (size_t)BATCH * KCONV;        // B*H*KCONV
    float* mh     = Lh + (size_t)BATCH * HH * KCONV;   // B*H
    float* s1     = mh + (size_t)BATCH * HH;           // B*128
    float* theme  = s1 + (size_t)BATCH * CHW;          // B*H
    float* convb  = theme + (size_t)BATCH * HH;        // B*H

    // zero initial h and c (adjacent)
    hipMemsetAsync(hbuf, 0, 2 * (size_t)BATCH * HH * sizeof(float), stream);

    prep_kernel<<<GDIM, 256, 0, stream>>>(kw, kb, rw, rb, Wp, tcoef, biasb);

    dim3 gmain((GDIM + BN - 1) / BN, BATCH / BM);   // (49, 16)
    for (int t = 0; t < TT; ++t) {
        gemm_nt<0><<<gmain, 256, 0, stream>>>(
            nullptr, 0, x, hbuf, t, Wp, KPACK, biasb, tcoef, timep,
            g, GDIM, BATCH, GDIM, KPACK);
        cell_kernel<<<BATCH, 256, 0, stream>>>(g, cbuf, hbuf, hwin, distp, t);
    }

    window_kernel<<<(BATCH + 255) / 256, 256, 0, stream>>>(distp, ld);
    localh_kernel<<<(BATCH * HH) / 256, 256, 0, stream>>>(hwin, ld, Lh, mh);

    // conv: [B, 7680] x [768, 7680]^T
    gemm_nt<1><<<dim3(HH / BN, BATCH / BM), 256, 0, stream>>>(
        Lh, HH * KCONV, nullptr, nullptr, 0, conv_w, HH * KCONV, conv_b,
        nullptr, nullptr, convb, HH, BATCH, HH, HH * KCONV);
    // scale (relu): [B, 768] x [128, 768]^T
    gemm_nt<2><<<dim3(CHW / BN, BATCH / BM), 256, 0, stream>>>(
        mh, HH, nullptr, nullptr, 0, scale_w, HH, scale_b,
        nullptr, nullptr, s1, CHW, BATCH, CHW, HH);
    // rescale (sigmoid): [B, 128] x [768, 128]^T
    gemm_nt<3><<<dim3(HH / BN, BATCH / BM), 256, 0, stream>>>(
        s1, CHW, nullptr, nullptr, 0, resc_w, CHW, resc_b,
        nullptr, nullptr, theme, HH, BATCH, HH, CHW);

    out_kernel<<<BATCH, 256, 0, stream>>>(theme, convb, hbuf, out_w, out_b, outp);
}

// Round 2
// 10198.666 us; speedup vs baseline: 5.2470x; 5.2470x over previous
//
#include <hip/hip_runtime.h>
#include <hip/hip_bf16.h>
#include <math.h>

// Problem constants
#define BATCH 1024
#define TT    256
#define DD    256
#define HH    768
#define LL    6
#define KCONV 10
#define CHW   128
#define GDIM  3084     // 4*H + 2*L
#define GP    3200     // GDIM padded to 25*128
#define KPACK 1024     // D + H

typedef __attribute__((ext_vector_type(8))) __bf16 bf16x8;
typedef __attribute__((ext_vector_type(4))) float f32x4;

__device__ __forceinline__ float sigf(float v) { return 1.0f / (1.0f + expf(-v)); }

// ---------------------------------------------------------------------------
// Pack Wpb[GP][1024] bf16 = [kernel_w[:, :256] | rec_w[:, :768]], pad rows = 0
// tcoef[j] = kw[j,256] + rw[j,768] ; bias[j] = kb[j] + rb[j]
// ---------------------------------------------------------------------------
__global__ __launch_bounds__(256) void prep_kernel(
    const float* __restrict__ kw, const float* __restrict__ kb,
    const float* __restrict__ rw, const float* __restrict__ rb,
    __hip_bfloat16* __restrict__ Wpb, float* __restrict__ tcoef, float* __restrict__ bias)
{
    int j = blockIdx.x;
    int tid = threadIdx.x;
#pragma unroll
    for (int k = 0; k < 4; ++k) {
        int col = tid + k * 256;
        float v = 0.0f;
        if (j < GDIM)
            v = (col < DD) ? kw[(size_t)j * (DD + 1) + col]
                           : rw[(size_t)j * (HH + 1) + (col - DD)];
        Wpb[(size_t)j * KPACK + col] = __hip_bfloat16(v);
    }
    if (tid == 0 && j < GDIM) {
        tcoef[j] = kw[(size_t)j * (DD + 1) + DD] + rw[(size_t)j * (HH + 1) + HH];
        bias[j]  = kb[j] + rb[j];
    }
}

// conv_w -> bf16
__global__ __launch_bounds__(256) void cvt_kernel(
    const float* __restrict__ src, __hip_bfloat16* __restrict__ dst, int n)
{
    int i = blockIdx.x * 256 + threadIdx.x;
    if (i < n) dst[i] = __hip_bfloat16(src[i]);
}

// Ab init: x part = x[:,0,:], h part = 0
__global__ __launch_bounds__(256) void init_ab(
    const float* __restrict__ x, __hip_bfloat16* __restrict__ Ab)
{
    int b = blockIdx.x, tid = threadIdx.x;
    Ab[(size_t)b * KPACK + tid] = __hip_bfloat16(x[(size_t)b * TT * DD + tid]);
#pragma unroll
    for (int j = 0; j < 3; ++j)
        Ab[(size_t)b * KPACK + DD + tid + j * 256] = __hip_bfloat16(0.0f);
}

// ---------------------------------------------------------------------------
// bf16 MFMA NT GEMM: C[M,N] fp32 = A[M,K]bf16 * W[N,K]bf16^T   (+bias if EPI)
// 128x128 tile, 256 threads = 4 waves (2x2), wave tile 64x64 = 4x4 16x16 frags
// M, N multiples of 128; K multiple of 32.
// ---------------------------------------------------------------------------
template <int EPI>
__global__ __launch_bounds__(256) void gemm_bf16(
    const __hip_bfloat16* __restrict__ A, int lda,
    const __hip_bfloat16* __restrict__ W, int ldw,
    const float* __restrict__ bias,
    float* __restrict__ C, int ldc, int Kdim)
{
    __shared__ unsigned short As[128 * 32];
    __shared__ unsigned short Bs[128 * 32];
    const int tid  = threadIdx.x;
    const int lane = tid & 63;
    const int wid  = tid >> 6;
    const int wr   = wid >> 1, wc = wid & 1;
    const size_t bm = (size_t)blockIdx.y * 128;
    const size_t bn = (size_t)blockIdx.x * 128;

    f32x4 acc[4][4];
#pragma unroll
    for (int m = 0; m < 4; ++m)
#pragma unroll
        for (int n = 0; n < 4; ++n) acc[m][n] = (f32x4){0.f, 0.f, 0.f, 0.f};

    // staging: 512 chunks of 16B per tile; thread handles chunk tid and tid+256
    const int l0 = tid, l1 = tid + 256;
    const __hip_bfloat16* gA0 = A + (bm + (l0 >> 2)) * (size_t)lda + (l0 & 3) * 8;
    const __hip_bfloat16* gA1 = A + (bm + (l1 >> 2)) * (size_t)lda + (l1 & 3) * 8;
    const __hip_bfloat16* gB0 = W + (bn + (l0 >> 2)) * (size_t)ldw + (l0 & 3) * 8;
    const __hip_bfloat16* gB1 = W + (bn + (l1 >> 2)) * (size_t)ldw + (l1 & 3) * 8;

    const int kg   = lane >> 4;            // k-group 0..3
    const int arow = wr * 64 + (lane & 15);
    const int brow = wc * 64 + (lane & 15);

    for (int k0 = 0; k0 < Kdim; k0 += 32) {
        bf16x8 ra0 = *(const bf16x8*)(gA0 + k0);
        bf16x8 ra1 = *(const bf16x8*)(gA1 + k0);
        bf16x8 rb0 = *(const bf16x8*)(gB0 + k0);
        bf16x8 rb1 = *(const bf16x8*)(gB1 + k0);
        __syncthreads();
        *(bf16x8*)&As[l0 * 8] = ra0;
        *(bf16x8*)&As[l1 * 8] = ra1;
        *(bf16x8*)&Bs[l0 * 8] = rb0;
        *(bf16x8*)&Bs[l1 * 8] = rb1;
        __syncthreads();

        bf16x8 af[4], bfv[4];
#pragma unroll
        for (int m = 0; m < 4; ++m)
            af[m] = *(const bf16x8*)&As[(arow + m * 16) * 32 + kg * 8];
#pragma unroll
        for (int n = 0; n < 4; ++n)
            bfv[n] = *(const bf16x8*)&Bs[(brow + n * 16) * 32 + kg * 8];
#pragma unroll
        for (int m = 0; m < 4; ++m)
#pragma unroll
            for (int n = 0; n < 4; ++n)
                acc[m][n] = __builtin_amdgcn_mfma_f32_16x16x32_bf16(
                    af[m], bfv[n], acc[m][n], 0, 0, 0);
    }

    // epilogue: C/D layout col = lane&15, row = (lane>>4)*4 + j
    const int crow0 = (int)bm + wr * 64 + (lane >> 4) * 4;
    const int ccol0 = (int)bn + wc * 64 + (lane & 15);
#pragma unroll
    for (int m = 0; m < 4; ++m) {
#pragma unroll
        for (int n = 0; n < 4; ++n) {
            int col = ccol0 + n * 16;
            float bv = (EPI == 1) ? bias[col] : 0.0f;
#pragma unroll
            for (int j = 0; j < 4; ++j) {
                int row = crow0 + m * 16 + j;
                C[(size_t)row * ldc + col] = acc[m][n][j] + bv;
            }
        }
    }
}

// ---------------------------------------------------------------------------
// fp32 NT GEMM for the tiny tail matmuls (64x64 tile).
// MODE 2: +bias, relu ; MODE 3: +bias, sigmoid
// ---------------------------------------------------------------------------
#define BM 64
#define BN 64
#define BK 32
template <int MODE>
__global__ __launch_bounds__(256) void gemm_nt(
    const float* __restrict__ A, int lda,
    const float* __restrict__ W, int ldw,
    const float* __restrict__ bias,
    float* __restrict__ C, int ldc, int M, int N, int Kdim)
{
    __shared__ float As[BK][BM + 4];
    __shared__ float Ws[BK][BN + 4];
    const int tid = threadIdx.x;
    const int bm = blockIdx.y * BM;
    const int bn = blockIdx.x * BN;
    const int tx = tid & 15;
    const int ty = tid >> 4;

    float acc[4][4];
#pragma unroll
    for (int i = 0; i < 4; ++i)
#pragma unroll
        for (int j = 0; j < 4; ++j) acc[i][j] = 0.0f;

    for (int k0 = 0; k0 < Kdim; k0 += BK) {
#pragma unroll
        for (int i = 0; i < (BM * BK) / 256; ++i) {
            int linear = tid + i * 256;
            int r = linear >> 5, kk = linear & 31;
            As[kk][r] = A[(size_t)(bm + r) * lda + k0 + kk];
        }
#pragma unroll
        for (int i = 0; i < (BN * BK) / 256; ++i) {
            int linear = tid + i * 256;
            int r = linear >> 5, kk = linear & 31;
            int gcol = bn + r;
            Ws[kk][r] = (gcol < N) ? W[(size_t)gcol * ldw + k0 + kk] : 0.0f;
        }
        __syncthreads();
#pragma unroll
        for (int kk = 0; kk < BK; ++kk) {
            float4 a4 = *(const float4*)&As[kk][ty * 4];
            float4 b4 = *(const float4*)&Ws[kk][tx * 4];
            float av[4] = {a4.x, a4.y, a4.z, a4.w};
            float bv[4] = {b4.x, b4.y, b4.z, b4.w};
#pragma unroll
            for (int i = 0; i < 4; ++i)
#pragma unroll
                for (int j = 0; j < 4; ++j)
                    acc[i][j] = fmaf(av[i], bv[j], acc[i][j]);
        }
        __syncthreads();
    }
#pragma unroll
    for (int i = 0; i < 4; ++i) {
        int row = bm + ty * 4 + i;
#pragma unroll
        for (int j = 0; j < 4; ++j) {
            int col = bn + tx * 4 + j;
            if (col < N) {
                float v = acc[i][j] + bias[col];
                if (MODE == 2) v = fmaxf(v, 0.0f);
                if (MODE == 3) v = sigf(v);
                C[(size_t)row * ldc + col] = v;
            }
        }
    }
}

// ---------------------------------------------------------------------------
// Cell update; folds bias + time*tcoef into the gate read; writes fp32 h/c,
// bf16 h into Ab[:,256:], bf16 x_{t+1} into Ab[:,0:256], hwin, dist.
// ---------------------------------------------------------------------------
__global__ __launch_bounds__(256) void cell_kernel(
    const float* __restrict__ g,     // [B, GP]
    const float* __restrict__ x,     // [B, T, D]
    const float* __restrict__ timep, // [B, T]
    const float* __restrict__ biasb, const float* __restrict__ tcoef,
    float* __restrict__ cbuf, float* __restrict__ hbuf,
    float* __restrict__ hwin, __hip_bfloat16* __restrict__ Ab,
    float* __restrict__ dist_out, int tstep)
{
    int b = blockIdx.x;
    const float* gr = g + (size_t)b * GP;
    const float tv = timep[(size_t)b * TT + tstep];

    float fv[LL], iv[LL];
    float mf = -1e30f, mi = -1e30f;
#pragma unroll
    for (int l = 0; l < LL; ++l) {
        fv[l] = gr[l] + biasb[l] + tv * tcoef[l];           mf = fmaxf(mf, fv[l]);
        iv[l] = gr[LL + l] + biasb[LL + l] + tv * tcoef[LL + l]; mi = fmaxf(mi, iv[l]);
    }
    float sf = 0.0f, si = 0.0f;
#pragma unroll
    for (int l = 0; l < LL; ++l) {
        fv[l] = expf(fv[l] - mf); sf += fv[l];
        iv[l] = expf(iv[l] - mi); si += iv[l];
    }
    float fm[LL], im[LL];
    float run = 0.0f;
#pragma unroll
    for (int l = 0; l < LL; ++l) { run += fv[l] / sf; fm[l] = run; }
    run = 0.0f;
#pragma unroll
    for (int l = LL - 1; l >= 0; --l) { run += iv[l] / si; im[l] = run; }
    float dist = 1.0f - (fm[0] + fm[1] + fm[2] + fm[3] + fm[4] + fm[5]) * (1.0f / 6.0f);

    int slot = tstep % KCONV;
    float* hw = hwin + (size_t)slot * BATCH * HH + (size_t)b * HH;

#pragma unroll
    for (int j = 0; j < 3; ++j) {
        int e = threadIdx.x + j * 256;
        int l = e >> 7;
        int c0 = 2 * LL + e;
        float fg = sigf(gr[c0] + biasb[c0] + tv * tcoef[c0]);
        int c1 = c0 + HH;
        float ig = sigf(gr[c1] + biasb[c1] + tv * tcoef[c1]);
        int c2 = c1 + HH;
        float og = sigf(gr[c2] + biasb[c2] + tv * tcoef[c2]);
        int c3 = c2 + HH;
        float ci = tanhf(gr[c3] + biasb[c3] + tv * tcoef[c3]);
        float cl = cbuf[(size_t)b * HH + e];
        float fmv = fm[l], imv = im[l];
        float ov = fmv * imv;
        float cn = ov * (fg * cl + ig * ci) + (fmv - ov) * cl + (imv - ov) * ci;
        float hn = og * tanhf(cn);
        cbuf[(size_t)b * HH + e] = cn;
        hbuf[(size_t)b * HH + e] = hn;
        hw[e] = hn;
        Ab[(size_t)b * KPACK + DD + e] = __hip_bfloat16(hn);
    }
    if (tstep + 1 < TT)
        Ab[(size_t)b * KPACK + threadIdx.x] =
            __hip_bfloat16(x[((size_t)b * TT + tstep + 1) * DD + threadIdx.x]);
    if (threadIdx.x == 0) dist_out[(size_t)tstep * BATCH + b] = dist;
}

// ---------------------------------------------------------------------------
__global__ __launch_bounds__(256) void window_kernel(
    const float* __restrict__ dist_out, float* __restrict__ ld)
{
    int b = blockIdx.x * blockDim.x + threadIdx.x;
    if (b >= BATCH) return;
    float w[KCONV];
    float run = 0.0f, m = -1e30f;
#pragma unroll
    for (int k = 0; k < KCONV; ++k) {
        run += dist_out[(size_t)(TT - KCONV + k) * BATCH + b];
        w[k] = run;
        m = fmaxf(m, run);
    }
    float s = 0.0f;
#pragma unroll
    for (int k = 0; k < KCONV; ++k) { w[k] = expf(w[k] - m); s += w[k]; }
    float inv = 1.0f / s;
#pragma unroll
    for (int k = 0; k < KCONV; ++k) ld[b * KCONV + k] = w[k] * inv;
}

// Lhb[b, e*KCONV + k] (bf16) and mh[b,e] = mean_k
__global__ __launch_bounds__(256) void localh_kernel(
    const float* __restrict__ hwin, const float* __restrict__ ld,
    __hip_bfloat16* __restrict__ Lhb, float* __restrict__ mh)
{
    int idx = blockIdx.x * 256 + threadIdx.x;
    int b = idx / HH;
    int e = idx - b * HH;
    float lv[KCONV];
#pragma unroll
    for (int k = 0; k < KCONV; ++k) lv[k] = ld[b * KCONV + k];
    float sum = 0.0f;
#pragma unroll
    for (int k = 0; k < KCONV; ++k) {
        int slot = (TT - KCONV + k) % KCONV;
        float v = hwin[(size_t)slot * BATCH * HH + (size_t)b * HH + e] * lv[k];
        Lhb[(size_t)b * (HH * KCONV) + e * KCONV + k] = __hip_bfloat16(v);
        sum += v;
    }
    mh[idx] = sum * (1.0f / KCONV);
}

__global__ __launch_bounds__(256) void out_kernel(
    const float* __restrict__ theme, const float* __restrict__ conv,
    const float* __restrict__ hbuf, const float* __restrict__ out_w,
    const float* __restrict__ out_b, float* __restrict__ out)
{
    __shared__ float red[256];
    int b = blockIdx.x;
    float p = 0.0f;
    for (int e = threadIdx.x; e < HH; e += 256)
        p += (theme[(size_t)b * HH + e] * conv[(size_t)b * HH + e] + hbuf[(size_t)b * HH + e]) * out_w[e];
    red[threadIdx.x] = p;
    __syncthreads();
    for (int s = 128; s > 0; s >>= 1) {
        if (threadIdx.x < s) red[threadIdx.x] += red[threadIdx.x + s];
        __syncthreads();
    }
    if (threadIdx.x == 0) out[b] = sigf(red[0] + out_b[0]);
}

// ---------------------------------------------------------------------------
extern "C" void kernel_launch(void* const* d_in, const int* in_sizes, int n_in,
                              void* d_out, int out_size, void* d_ws, size_t ws_size,
                              hipStream_t stream)
{
    const float* x       = (const float*)d_in[0];
    const float* timep   = (const float*)d_in[1];
    const float* kw      = (const float*)d_in[2];
    const float* kb      = (const float*)d_in[3];
    const float* rw      = (const float*)d_in[4];
    const float* rb      = (const float*)d_in[5];
    const float* scale_w = (const float*)d_in[6];
    const float* scale_b = (const float*)d_in[7];
    const float* resc_w  = (const float*)d_in[8];
    const float* resc_b  = (const float*)d_in[9];
    const float* conv_w  = (const float*)d_in[10];
    const float* conv_b  = (const float*)d_in[11];
    const float* out_w   = (const float*)d_in[12];
    const float* out_b   = (const float*)d_in[13];

    float* outp  = (float*)d_out;
    float* distp = outp + BATCH;

    // workspace carve (256B-aligned chunks)
    char* cur = (char*)d_ws;
    auto carve = [&](size_t bytes) {
        char* p = cur;
        cur += (bytes + 255) & ~(size_t)255;
        return (void*)p;
    };
    __hip_bfloat16* Wpb   = (__hip_bfloat16*)carve((size_t)GP * KPACK * 2);
    __hip_bfloat16* Ab    = (__hip_bfloat16*)carve((size_t)BATCH * KPACK * 2);
    __hip_bfloat16* Lhb   = (__hip_bfloat16*)carve((size_t)BATCH * HH * KCONV * 2);
    __hip_bfloat16* convwb= (__hip_bfloat16*)carve((size_t)HH * HH * KCONV * 2);
    float* tcoef = (float*)carve(GDIM * 4);
    float* biasb = (float*)carve(GDIM * 4);
    float* g     = (float*)carve((size_t)BATCH * GP * 4);
    float* hbuf  = (float*)carve((size_t)BATCH * HH * 4);
    float* cbuf  = (float*)carve((size_t)BATCH * HH * 4);
    float* hwin  = (float*)carve((size_t)KCONV * BATCH * HH * 4);
    float* ld    = (float*)carve((size_t)BATCH * KCONV * 4);
    float* mh    = (float*)carve((size_t)BATCH * HH * 4);
    float* s1    = (float*)carve((size_t)BATCH * CHW * 4);
    float* theme = (float*)carve((size_t)BATCH * HH * 4);
    float* convb = (float*)carve((size_t)BATCH * HH * 4);

    hipMemsetAsync(hbuf, 0, 2 * (size_t)BATCH * HH * sizeof(float), stream);
    prep_kernel<<<GP, 256, 0, stream>>>(kw, kb, rw, rb, Wpb, tcoef, biasb);
    cvt_kernel<<<(HH * HH * KCONV + 255) / 256, 256, 0, stream>>>(
        conv_w, convwb, HH * HH * KCONV);
    init_ab<<<BATCH, 256, 0, stream>>>(x, Ab);

    dim3 gmain(GP / 128, BATCH / 128);   // (25, 8)
    for (int t = 0; t < TT; ++t) {
        gemm_bf16<0><<<gmain, 256, 0, stream>>>(
            Ab, KPACK, Wpb, KPACK, nullptr, g, GP, KPACK);
        cell_kernel<<<BATCH, 256, 0, stream>>>(
            g, x, timep, biasb, tcoef, cbuf, hbuf, hwin, Ab, distp, t);
    }

    window_kernel<<<(BATCH + 255) / 256, 256, 0, stream>>>(distp, ld);
    localh_kernel<<<(BATCH * HH) / 256, 256, 0, stream>>>(hwin, ld, Lhb, mh);

    // conv: [B,7680]bf16 x [768,7680]bf16^T (+conv_b)
    gemm_bf16<1><<<dim3(HH / 128, BATCH / 128), 256, 0, stream>>>(
        Lhb, HH * KCONV, convwb, HH * KCONV, conv_b, convb, HH, HH * KCONV);
    // scale (relu): [B,768] x [128,768]^T
    gemm_nt<2><<<dim3(CHW / BN, BATCH / BM), 256, 0, stream>>>(
        mh, HH, scale_w, HH, scale_b, s1, CHW, BATCH, CHW, HH);
    // rescale (sigmoid): [B,128] x [768,128]^T
    gemm_nt<3><<<dim3(HH / BN, BATCH / BM), 256, 0, stream>>>(
        s1, CHW, resc_w, CHW, resc_b, theme, HH, BATCH, HH, CHW);

    out_kernel<<<BATCH, 256, 0, stream>>>(theme, convb, hbuf, out_w, out_b, outp);
}

// Round 3
// 7879.385 us; speedup vs baseline: 6.7914x; 1.2943x over previous
//
#include <hip/hip_runtime.h>
#include <hip/hip_bf16.h>
#include <math.h>

// Problem constants
#define BATCH 1024
#define TT    256
#define DD    256
#define HH    768
#define LL    6
#define KCONV 10
#define CHW   128
#define GDIM  3084     // 4*H + 2*L
#define GP    3200     // GDIM padded to 25*128
#define KPACK 1024     // D + H

typedef __attribute__((ext_vector_type(8))) __bf16 bf16x8;
typedef __attribute__((ext_vector_type(4))) float f32x4;

__device__ __forceinline__ float sigf(float v) { return 1.0f / (1.0f + expf(-v)); }

// async global->LDS, 16B per lane. LDS dest is wave-uniform base + lane*16,
// which our chunk layout matches exactly (chunk tid at byte tid*16).
__device__ __forceinline__ void gload16(const void* g, void* l) {
    __builtin_amdgcn_global_load_lds(
        (const __attribute__((address_space(1))) unsigned int*)g,
        (__attribute__((address_space(3))) unsigned int*)l, 16, 0, 0);
}

// ---------------------------------------------------------------------------
// Pack Wpb[GP][1024] bf16 = [kernel_w[:, :256] | rec_w[:, :768]], pad rows = 0
// ---------------------------------------------------------------------------
__global__ __launch_bounds__(256) void prep_kernel(
    const float* __restrict__ kw, const float* __restrict__ kb,
    const float* __restrict__ rw, const float* __restrict__ rb,
    __hip_bfloat16* __restrict__ Wpb, float* __restrict__ tcoef, float* __restrict__ bias)
{
    int j = blockIdx.x;
    int tid = threadIdx.x;
#pragma unroll
    for (int k = 0; k < 4; ++k) {
        int col = tid + k * 256;
        float v = 0.0f;
        if (j < GDIM)
            v = (col < DD) ? kw[(size_t)j * (DD + 1) + col]
                           : rw[(size_t)j * (HH + 1) + (col - DD)];
        Wpb[(size_t)j * KPACK + col] = __hip_bfloat16(v);
    }
    if (tid == 0 && j < GDIM) {
        tcoef[j] = kw[(size_t)j * (DD + 1) + DD] + rw[(size_t)j * (HH + 1) + HH];
        bias[j]  = kb[j] + rb[j];
    }
}

__global__ __launch_bounds__(256) void cvt_kernel(
    const float* __restrict__ src, __hip_bfloat16* __restrict__ dst, int n)
{
    int i = blockIdx.x * 256 + threadIdx.x;
    if (i < n) dst[i] = __hip_bfloat16(src[i]);
}

__global__ __launch_bounds__(256) void init_ab(
    const float* __restrict__ x, __hip_bfloat16* __restrict__ Ab)
{
    int b = blockIdx.x, tid = threadIdx.x;
    Ab[(size_t)b * KPACK + tid] = __hip_bfloat16(x[(size_t)b * TT * DD + tid]);
#pragma unroll
    for (int j = 0; j < 3; ++j)
        Ab[(size_t)b * KPACK + DD + tid + j * 256] = __hip_bfloat16(0.0f);
}

// ---------------------------------------------------------------------------
// m97-style bf16 MFMA NT GEMM with K-split.
// C_z[M,N] += A[M, kspan] * W[N, kspan]^T   for z = 0..SPLIT-1
// 128x128 tile, 256 threads = 4 waves (2x2), wave tile 64x64.
// Staging via global_load_lds dwordx4 (linear LDS, 2 chunks/thread/operand).
// Grid: nbn*8*SPLIT blocks, XCD-swizzled; id = (bn*8 + bm)*SPLIT + z so each
// XCD's chunk shares W column panels (L2-resident working set).
// ---------------------------------------------------------------------------
template <int SPLIT>
__global__ __launch_bounds__(256, 2) void gemm_mfma(
    const __hip_bfloat16* __restrict__ A, int lda,
    const __hip_bfloat16* __restrict__ W, int ldw,
    float* __restrict__ C, int ldc, size_t cstride, int Kdim, int nbn)
{
    __shared__ unsigned short As[128 * 32];
    __shared__ unsigned short Bs[128 * 32];

    const int nwg = nbn * 8 * SPLIT;
    const int cpx = nwg >> 3;                    // nwg % 8 == 0
    const int bid = blockIdx.x;
    const int swz = (bid & 7) * cpx + (bid >> 3);
    const int z   = swz % SPLIT;
    const int bmn = swz / SPLIT;
    const int bm  = bmn % 8;
    const int bn  = bmn / 8;
    const int kspan = Kdim / SPLIT;

    const int tid  = threadIdx.x;
    const int lane = tid & 63;
    const int wid  = tid >> 6;
    const int wr   = wid >> 1, wc = wid & 1;
    const int kg   = lane >> 4;
    const int r15  = lane & 15;

    f32x4 acc[4][4];
#pragma unroll
    for (int m = 0; m < 4; ++m)
#pragma unroll
        for (int n = 0; n < 4; ++n) acc[m][n] = (f32x4){0.f, 0.f, 0.f, 0.f};

    const __hip_bfloat16* Abase = A + (size_t)(bm * 128) * lda + (size_t)z * kspan;
    const __hip_bfloat16* Wbase = W + (size_t)(bn * 128) * ldw + (size_t)z * kspan;
    const int c0 = tid, c1 = tid + 256;          // 16B chunks of the 128x32 tile
    const size_t sA0 = (size_t)(c0 >> 2) * lda + (c0 & 3) * 8;
    const size_t sA1 = (size_t)(c1 >> 2) * lda + (c1 & 3) * 8;
    const size_t sB0 = (size_t)(c0 >> 2) * ldw + (c0 & 3) * 8;
    const size_t sB1 = (size_t)(c1 >> 2) * ldw + (c1 & 3) * 8;

    for (int k0 = 0; k0 < kspan; k0 += 32) {
        gload16(Abase + sA0 + k0, &As[c0 * 8]);
        gload16(Abase + sA1 + k0, &As[c0 * 8 + 2048]);
        gload16(Wbase + sB0 + k0, &Bs[c0 * 8]);
        gload16(Wbase + sB1 + k0, &Bs[c0 * 8 + 2048]);
        __syncthreads();   // drains vmcnt; tile visible to all waves

        bf16x8 af[4], bv[4];
#pragma unroll
        for (int m = 0; m < 4; ++m)
            af[m] = *(const bf16x8*)&As[(wr * 64 + r15 + m * 16) * 32 + kg * 8];
#pragma unroll
        for (int n = 0; n < 4; ++n)
            bv[n] = *(const bf16x8*)&Bs[(wc * 64 + r15 + n * 16) * 32 + kg * 8];
#pragma unroll
        for (int m = 0; m < 4; ++m)
#pragma unroll
            for (int n = 0; n < 4; ++n)
                acc[m][n] = __builtin_amdgcn_mfma_f32_16x16x32_bf16(
                    af[m], bv[n], acc[m][n], 0, 0, 0);
        __syncthreads();   // all reads done before next iter overwrites
    }

    float* Cp = C + (size_t)z * cstride;
    const int crow0 = bm * 128 + wr * 64 + (lane >> 4) * 4;
    const int ccol0 = bn * 128 + wc * 64 + r15;
#pragma unroll
    for (int m = 0; m < 4; ++m)
#pragma unroll
        for (int n = 0; n < 4; ++n)
#pragma unroll
            for (int j = 0; j < 4; ++j)
                Cp[(size_t)(crow0 + m * 16 + j) * ldc + ccol0 + n * 16] = acc[m][n][j];
}

// ---------------------------------------------------------------------------
// fp32 NT GEMM for the tiny tail matmuls. MODE 2: relu ; MODE 3: sigmoid
// ---------------------------------------------------------------------------
#define BM 64
#define BN 64
#define BK 32
template <int MODE>
__global__ __launch_bounds__(256) void gemm_nt(
    const float* __restrict__ A, int lda,
    const float* __restrict__ W, int ldw,
    const float* __restrict__ bias,
    float* __restrict__ C, int ldc, int M, int N, int Kdim)
{
    __shared__ float As[BK][BM + 4];
    __shared__ float Ws[BK][BN + 4];
    const int tid = threadIdx.x;
    const int bm = blockIdx.y * BM;
    const int bn = blockIdx.x * BN;
    const int tx = tid & 15;
    const int ty = tid >> 4;

    float acc[4][4];
#pragma unroll
    for (int i = 0; i < 4; ++i)
#pragma unroll
        for (int j = 0; j < 4; ++j) acc[i][j] = 0.0f;

    for (int k0 = 0; k0 < Kdim; k0 += BK) {
#pragma unroll
        for (int i = 0; i < (BM * BK) / 256; ++i) {
            int linear = tid + i * 256;
            int r = linear >> 5, kk = linear & 31;
            As[kk][r] = A[(size_t)(bm + r) * lda + k0 + kk];
        }
#pragma unroll
        for (int i = 0; i < (BN * BK) / 256; ++i) {
            int linear = tid + i * 256;
            int r = linear >> 5, kk = linear & 31;
            int gcol = bn + r;
            Ws[kk][r] = (gcol < N) ? W[(size_t)gcol * ldw + k0 + kk] : 0.0f;
        }
        __syncthreads();
#pragma unroll
        for (int kk = 0; kk < BK; ++kk) {
            float4 a4 = *(const float4*)&As[kk][ty * 4];
            float4 b4 = *(const float4*)&Ws[kk][tx * 4];
            float av[4] = {a4.x, a4.y, a4.z, a4.w};
            float bv[4] = {b4.x, b4.y, b4.z, b4.w};
#pragma unroll
            for (int i = 0; i < 4; ++i)
#pragma unroll
                for (int j = 0; j < 4; ++j)
                    acc[i][j] = fmaf(av[i], bv[j], acc[i][j]);
        }
        __syncthreads();
    }
#pragma unroll
    for (int i = 0; i < 4; ++i) {
        int row = bm + ty * 4 + i;
#pragma unroll
        for (int j = 0; j < 4; ++j) {
            int col = bn + tx * 4 + j;
            if (col < N) {
                float v = acc[i][j] + bias[col];
                if (MODE == 2) v = fmaxf(v, 0.0f);
                if (MODE == 3) v = sigf(v);
                C[(size_t)row * ldc + col] = v;
            }
        }
    }
}

// ---------------------------------------------------------------------------
// Cell update: sums the two K-split partials of g, applies bias + time*tcoef,
// gates, c/h update, distance, sliding-window and next-step A writes.
// ---------------------------------------------------------------------------
__global__ __launch_bounds__(256) void cell_kernel(
    const float* __restrict__ g,     // [2][B, GP] partials
    size_t gstride,
    const float* __restrict__ x,     // [B, T, D]
    const float* __restrict__ timep, // [B, T]
    const float* __restrict__ biasb, const float* __restrict__ tcoef,
    float* __restrict__ cbuf, float* __restrict__ hbuf,
    float* __restrict__ hwin, __hip_bfloat16* __restrict__ Ab,
    float* __restrict__ dist_out, int tstep)
{
    int b = blockIdx.x;
    const float* gr0 = g + (size_t)b * GP;
    const float* gr1 = gr0 + gstride;
    const float tv = timep[(size_t)b * TT + tstep];

    float fv[LL], iv[LL];
    float mf = -1e30f, mi = -1e30f;
#pragma unroll
    for (int l = 0; l < LL; ++l) {
        fv[l] = gr0[l] + gr1[l] + biasb[l] + tv * tcoef[l];
        mf = fmaxf(mf, fv[l]);
        iv[l] = gr0[LL + l] + gr1[LL + l] + biasb[LL + l] + tv * tcoef[LL + l];
        mi = fmaxf(mi, iv[l]);
    }
    float sf = 0.0f, si = 0.0f;
#pragma unroll
    for (int l = 0; l < LL; ++l) {
        fv[l] = expf(fv[l] - mf); sf += fv[l];
        iv[l] = expf(iv[l] - mi); si += iv[l];
    }
    float fm[LL], im[LL];
    float run = 0.0f;
#pragma unroll
    for (int l = 0; l < LL; ++l) { run += fv[l] / sf; fm[l] = run; }
    run = 0.0f;
#pragma unroll
    for (int l = LL - 1; l >= 0; --l) { run += iv[l] / si; im[l] = run; }
    float dist = 1.0f - (fm[0] + fm[1] + fm[2] + fm[3] + fm[4] + fm[5]) * (1.0f / 6.0f);

    int slot = tstep % KCONV;
    float* hw = hwin + (size_t)slot * BATCH * HH + (size_t)b * HH;

#pragma unroll
    for (int j = 0; j < 3; ++j) {
        int e = threadIdx.x + j * 256;
        int l = e >> 7;
        int c0 = 2 * LL + e;
        int c1 = c0 + HH, c2 = c1 + HH, c3 = c2 + HH;
        float fg = sigf(gr0[c0] + gr1[c0] + biasb[c0] + tv * tcoef[c0]);
        float ig = sigf(gr0[c1] + gr1[c1] + biasb[c1] + tv * tcoef[c1]);
        float og = sigf(gr0[c2] + gr1[c2] + biasb[c2] + tv * tcoef[c2]);
        float ci = tanhf(gr0[c3] + gr1[c3] + biasb[c3] + tv * tcoef[c3]);
        float cl = cbuf[(size_t)b * HH + e];
        float fmv = fm[l], imv = im[l];
        float ov = fmv * imv;
        float cn = ov * (fg * cl + ig * ci) + (fmv - ov) * cl + (imv - ov) * ci;
        float hn = og * tanhf(cn);
        cbuf[(size_t)b * HH + e] = cn;
        hbuf[(size_t)b * HH + e] = hn;
        hw[e] = hn;
        Ab[(size_t)b * KPACK + DD + e] = __hip_bfloat16(hn);
    }
    if (tstep + 1 < TT)
        Ab[(size_t)b * KPACK + threadIdx.x] =
            __hip_bfloat16(x[((size_t)b * TT + tstep + 1) * DD + threadIdx.x]);
    if (threadIdx.x == 0) dist_out[(size_t)tstep * BATCH + b] = dist;
}

// ---------------------------------------------------------------------------
__global__ __launch_bounds__(256) void window_kernel(
    const float* __restrict__ dist_out, float* __restrict__ ld)
{
    int b = blockIdx.x * blockDim.x + threadIdx.x;
    if (b >= BATCH) return;
    float w[KCONV];
    float run = 0.0f, m = -1e30f;
#pragma unroll
    for (int k = 0; k < KCONV; ++k) {
        run += dist_out[(size_t)(TT - KCONV + k) * BATCH + b];
        w[k] = run;
        m = fmaxf(m, run);
    }
    float s = 0.0f;
#pragma unroll
    for (int k = 0; k < KCONV; ++k) { w[k] = expf(w[k] - m); s += w[k]; }
    float inv = 1.0f / s;
#pragma unroll
    for (int k = 0; k < KCONV; ++k) ld[b * KCONV + k] = w[k] * inv;
}

__global__ __launch_bounds__(256) void localh_kernel(
    const float* __restrict__ hwin, const float* __restrict__ ld,
    __hip_bfloat16* __restrict__ Lhb, float* __restrict__ mh)
{
    int idx = blockIdx.x * 256 + threadIdx.x;
    int b = idx / HH;
    int e = idx - b * HH;
    float lv[KCONV];
#pragma unroll
    for (int k = 0; k < KCONV; ++k) lv[k] = ld[b * KCONV + k];
    float sum = 0.0f;
#pragma unroll
    for (int k = 0; k < KCONV; ++k) {
        int slot = (TT - KCONV + k) % KCONV;
        float v = hwin[(size_t)slot * BATCH * HH + (size_t)b * HH + e] * lv[k];
        Lhb[(size_t)b * (HH * KCONV) + e * KCONV + k] = __hip_bfloat16(v);
        sum += v;
    }
    mh[idx] = sum * (1.0f / KCONV);
}

// output[b] = sigmoid( sum_e (theme*(sum_z convp_z + conv_b) + h_last)*out_w + out_b )
__global__ __launch_bounds__(256) void out_kernel(
    const float* __restrict__ theme, const float* __restrict__ convp, size_t cstride,
    const float* __restrict__ conv_b, const float* __restrict__ hbuf,
    const float* __restrict__ out_w, const float* __restrict__ out_b,
    float* __restrict__ out)
{
    __shared__ float red[256];
    int b = blockIdx.x;
    float p = 0.0f;
    for (int e = threadIdx.x; e < HH; e += 256) {
        float cv = conv_b[e];
#pragma unroll
        for (int zz = 0; zz < 4; ++zz)
            cv += convp[(size_t)zz * cstride + (size_t)b * HH + e];
        p += (theme[(size_t)b * HH + e] * cv + hbuf[(size_t)b * HH + e]) * out_w[e];
    }
    red[threadIdx.x] = p;
    __syncthreads();
    for (int s = 128; s > 0; s >>= 1) {
        if (threadIdx.x < s) red[threadIdx.x] += red[threadIdx.x + s];
        __syncthreads();
    }
    if (threadIdx.x == 0) out[b] = sigf(red[0] + out_b[0]);
}

// ---------------------------------------------------------------------------
extern "C" void kernel_launch(void* const* d_in, const int* in_sizes, int n_in,
                              void* d_out, int out_size, void* d_ws, size_t ws_size,
                              hipStream_t stream)
{
    const float* x       = (const float*)d_in[0];
    const float* timep   = (const float*)d_in[1];
    const float* kw      = (const float*)d_in[2];
    const float* kb      = (const float*)d_in[3];
    const float* rw      = (const float*)d_in[4];
    const float* rb      = (const float*)d_in[5];
    const float* scale_w = (const float*)d_in[6];
    const float* scale_b = (const float*)d_in[7];
    const float* resc_w  = (const float*)d_in[8];
    const float* resc_b  = (const float*)d_in[9];
    const float* conv_w  = (const float*)d_in[10];
    const float* conv_b  = (const float*)d_in[11];
    const float* out_w   = (const float*)d_in[12];
    const float* out_b   = (const float*)d_in[13];

    float* outp  = (float*)d_out;
    float* distp = outp + BATCH;

    char* cur = (char*)d_ws;
    auto carve = [&](size_t bytes) {
        char* p = cur;
        cur += (bytes + 255) & ~(size_t)255;
        return (void*)p;
    };
    __hip_bfloat16* Wpb    = (__hip_bfloat16*)carve((size_t)GP * KPACK * 2);
    __hip_bfloat16* Ab     = (__hip_bfloat16*)carve((size_t)BATCH * KPACK * 2);
    __hip_bfloat16* Lhb    = (__hip_bfloat16*)carve((size_t)BATCH * HH * KCONV * 2);
    __hip_bfloat16* convwb = (__hip_bfloat16*)carve((size_t)HH * HH * KCONV * 2);
    float* tcoef = (float*)carve(GDIM * 4);
    float* biasb = (float*)carve(GDIM * 4);
    float* g     = (float*)carve(2 * (size_t)BATCH * GP * 4);      // 2 K-split partials
    float* hbuf  = (float*)carve((size_t)BATCH * HH * 4);
    float* cbuf  = (float*)carve((size_t)BATCH * HH * 4);
    float* hwin  = (float*)carve((size_t)KCONV * BATCH * HH * 4);
    float* ld    = (float*)carve((size_t)BATCH * KCONV * 4);
    float* mh    = (float*)carve((size_t)BATCH * HH * 4);
    float* s1    = (float*)carve((size_t)BATCH * CHW * 4);
    float* theme = (float*)carve((size_t)BATCH * HH * 4);
    float* convp = (float*)carve(4 * (size_t)BATCH * HH * 4);      // 4 conv partials

    hipMemsetAsync(hbuf, 0, 2 * (size_t)BATCH * HH * sizeof(float), stream);
    prep_kernel<<<GP, 256, 0, stream>>>(kw, kb, rw, rb, Wpb, tcoef, biasb);
    cvt_kernel<<<(HH * HH * KCONV + 255) / 256, 256, 0, stream>>>(
        conv_w, convwb, HH * HH * KCONV);
    init_ab<<<BATCH, 256, 0, stream>>>(x, Ab);

    const size_t gstride = (size_t)BATCH * GP;
    for (int t = 0; t < TT; ++t) {
        gemm_mfma<2><<<25 * 8 * 2, 256, 0, stream>>>(
            Ab, KPACK, Wpb, KPACK, g, GP, gstride, KPACK, 25);
        cell_kernel<<<BATCH, 256, 0, stream>>>(
            g, gstride, x, timep, biasb, tcoef, cbuf, hbuf, hwin, Ab, distp, t);
    }

    window_kernel<<<(BATCH + 255) / 256, 256, 0, stream>>>(distp, ld);
    localh_kernel<<<(BATCH * HH) / 256, 256, 0, stream>>>(hwin, ld, Lhb, mh);

    // conv einsum: [B,7680]bf16 x [768,7680]bf16^T, K-split x4
    gemm_mfma<4><<<6 * 8 * 4, 256, 0, stream>>>(
        Lhb, HH * KCONV, convwb, HH * KCONV, convp, HH, (size_t)BATCH * HH,
        HH * KCONV, 6);
    // scale (relu): [B,768] x [128,768]^T
    gemm_nt<2><<<dim3(CHW / BN, BATCH / BM), 256, 0, stream>>>(
        mh, HH, scale_w, HH, scale_b, s1, CHW, BATCH, CHW, HH);
    // rescale (sigmoid): [B,128] x [768,128]^T
    gemm_nt<3><<<dim3(HH / BN, BATCH / BM), 256, 0, stream>>>(
        s1, CHW, resc_w, CHW, resc_b, theme, HH, BATCH, HH, CHW);

    out_kernel<<<BATCH, 256, 0, stream>>>(
        theme, convp, (size_t)BATCH * HH, conv_b, hbuf, out_w, out_b, outp);
}

// Round 4
// 7567.984 us; speedup vs baseline: 7.0709x; 1.0411x over previous
//
#include <hip/hip_runtime.h>
#include <hip/hip_bf16.h>
#include <math.h>

// Problem constants
#define BATCH 1024
#define TT    256
#define DD    256
#define HH    768
#define LL    6
#define KCONV 10
#define CHW   128
#define GDIM  3084     // 4*H + 2*L
#define GP    3200     // GDIM padded to 25*128
#define KPACK 1024     // D + H

typedef __attribute__((ext_vector_type(8))) __bf16 bf16x8;
typedef __attribute__((ext_vector_type(4))) float f32x4;

__device__ __forceinline__ float sigf(float v) { return 1.0f / (1.0f + expf(-v)); }

// async global->LDS, 16B per lane; LDS dest = wave-uniform base + lane*16
__device__ __forceinline__ void gload16(const void* g, void* l) {
    __builtin_amdgcn_global_load_lds(
        (const __attribute__((address_space(1))) unsigned int*)g,
        (__attribute__((address_space(3))) unsigned int*)l, 16, 0, 0);
}

// ---------------------------------------------------------------------------
// Pack Wpb[GP][1024] bf16 = [kernel_w[:, :256] | rec_w[:, :768]], pad rows = 0
// ---------------------------------------------------------------------------
__global__ __launch_bounds__(256) void prep_kernel(
    const float* __restrict__ kw, const float* __restrict__ kb,
    const float* __restrict__ rw, const float* __restrict__ rb,
    __hip_bfloat16* __restrict__ Wpb, float* __restrict__ tcoef, float* __restrict__ bias)
{
    int j = blockIdx.x;
    int tid = threadIdx.x;
#pragma unroll
    for (int k = 0; k < 4; ++k) {
        int col = tid + k * 256;
        float v = 0.0f;
        if (j < GDIM)
            v = (col < DD) ? kw[(size_t)j * (DD + 1) + col]
                           : rw[(size_t)j * (HH + 1) + (col - DD)];
        Wpb[(size_t)j * KPACK + col] = __hip_bfloat16(v);
    }
    if (tid == 0 && j < GDIM) {
        tcoef[j] = kw[(size_t)j * (DD + 1) + DD] + rw[(size_t)j * (HH + 1) + HH];
        bias[j]  = kb[j] + rb[j];
    }
}

__global__ __launch_bounds__(256) void cvt_kernel(
    const float* __restrict__ src, __hip_bfloat16* __restrict__ dst, int n)
{
    int i = blockIdx.x * 256 + threadIdx.x;
    if (i < n) dst[i] = __hip_bfloat16(src[i]);
}

__global__ __launch_bounds__(256) void init_ab(
    const float* __restrict__ x, __hip_bfloat16* __restrict__ Ab)
{
    int b = blockIdx.x, tid = threadIdx.x;
    Ab[(size_t)b * KPACK + tid] = __hip_bfloat16(x[(size_t)b * TT * DD + tid]);
#pragma unroll
    for (int j = 0; j < 3; ++j)
        Ab[(size_t)b * KPACK + DD + tid + j * 256] = __hip_bfloat16(0.0f);
}

// ---------------------------------------------------------------------------
// bf16 MFMA NT GEMM, 64x128 tile, 4 waves (2x2), wave tile 32x64.
// BK=64, double-buffered LDS, global_load_lds staging with counted vmcnt
// (T3/T4: next tile's loads stay in flight across the barrier), and T2
// XOR-swizzle (linear LDS dest + pre-swizzled global source + swizzled read)
// to kill the 16-way ds_read_b128 bank conflict.
// Optional K-split (SPLIT partial outputs at C + z*cstride).
// Grid: nbm*nbn*SPLIT, XCD-swizzled; id = (bn*nbm + bm)*SPLIT + z so each
// XCD's chunk shares W column panels.
// ---------------------------------------------------------------------------
template <int SPLIT>
__global__ __launch_bounds__(256, 2) void gemm_mfma(
    const __hip_bfloat16* __restrict__ A, int lda,
    const __hip_bfloat16* __restrict__ W, int ldw,
    float* __restrict__ C, int ldc, size_t cstride, int Kdim, int nbm, int nbn)
{
    __shared__ unsigned short As[2][64 * 64];    // 8KB x2
    __shared__ unsigned short Bs[2][128 * 64];   // 16KB x2

    const int nwg = nbm * nbn * SPLIT;
    const int cpx = nwg >> 3;                    // nwg % 8 == 0
    const int bid = blockIdx.x;
    const int swz = (bid & 7) * cpx + (bid >> 3);
    const int z   = swz % SPLIT;
    const int t2  = swz / SPLIT;
    const int bm  = t2 % nbm;
    const int bn  = t2 / nbm;
    const int kspan = Kdim / SPLIT;

    const int tid  = threadIdx.x;
    const int lane = tid & 63;
    const int wid  = tid >> 6;
    const int wr   = wid >> 1, wc = wid & 1;
    const int kg   = lane >> 4;
    const int r15  = lane & 15;

    f32x4 acc[2][4];
#pragma unroll
    for (int m = 0; m < 2; ++m)
#pragma unroll
        for (int n = 0; n < 4; ++n) acc[m][n] = (f32x4){0.f, 0.f, 0.f, 0.f};

    const __hip_bfloat16* Abase = A + (size_t)(bm * 64) * lda + (size_t)z * kspan;
    const __hip_bfloat16* Wbase = W + (size_t)(bn * 128) * ldw + (size_t)z * kspan;

    // stage one BK=64 tile pair into buf; global chunk col pre-swizzled so a
    // linear LDS write yields the swizzled layout (rule #21).
    auto stage = [&](int buf, int k0) {
        unsigned short* Ad = &As[buf][0];
        unsigned short* Bd = &Bs[buf][0];
#pragma unroll
        for (int i = 0; i < 2; ++i) {            // A: 512 chunks (64 rows x 8)
            int c = tid + i * 256;
            int row = c >> 3, kc = c & 7;
            gload16(Abase + (size_t)row * lda + k0 + ((kc ^ (row & 7)) * 8),
                    Ad + c * 8);
        }
#pragma unroll
        for (int i = 0; i < 4; ++i) {            // B: 1024 chunks (128 rows x 8)
            int c = tid + i * 256;
            int row = c >> 3, kc = c & 7;
            gload16(Wbase + (size_t)row * ldw + k0 + ((kc ^ (row & 7)) * 8),
                    Bd + c * 8);
        }
    };

    const int NIT = kspan / 64;
    stage(0, 0);
    int cur = 0;
    for (int it = 0; it < NIT; ++it) {
        if (it + 1 < NIT) {
            stage(cur ^ 1, (it + 1) * 64);
            asm volatile("s_waitcnt vmcnt(6)" ::: "memory");  // cur's 6 done
        } else {
            asm volatile("s_waitcnt vmcnt(0)" ::: "memory");
        }
        __builtin_amdgcn_s_barrier();

#pragma unroll
        for (int ks = 0; ks < 2; ++ks) {
            const int kb = ks * 4 + kg;          // chunk col (pre-swizzle)
            bf16x8 af[2], bv[4];
#pragma unroll
            for (int m = 0; m < 2; ++m) {
                int ar = wr * 32 + m * 16 + r15;
                af[m] = *(const bf16x8*)&As[cur][ar * 64 + ((kb ^ (ar & 7)) * 8)];
            }
#pragma unroll
            for (int n = 0; n < 4; ++n) {
                int br = wc * 64 + n * 16 + r15;
                bv[n] = *(const bf16x8*)&Bs[cur][br * 64 + ((kb ^ (br & 7)) * 8)];
            }
#pragma unroll
            for (int m = 0; m < 2; ++m)
#pragma unroll
                for (int n = 0; n < 4; ++n)
                    acc[m][n] = __builtin_amdgcn_mfma_f32_16x16x32_bf16(
                        af[m], bv[n], acc[m][n], 0, 0, 0);
        }
        __builtin_amdgcn_s_barrier();            // all reads done before overwrite
        cur ^= 1;
    }

    float* Cp = C + (size_t)z * cstride;
    const int crow0 = bm * 64 + wr * 32 + (lane >> 4) * 4;
    const int ccol0 = bn * 128 + wc * 64 + r15;
#pragma unroll
    for (int m = 0; m < 2; ++m)
#pragma unroll
        for (int n = 0; n < 4; ++n)
#pragma unroll
            for (int j = 0; j < 4; ++j)
                Cp[(size_t)(crow0 + m * 16 + j) * ldc + ccol0 + n * 16] = acc[m][n][j];
}

// ---------------------------------------------------------------------------
// fp32 NT GEMM for the tiny tail matmuls. MODE 2: relu ; MODE 3: sigmoid
// ---------------------------------------------------------------------------
#define BM 64
#define BN 64
#define BK 32
template <int MODE>
__global__ __launch_bounds__(256) void gemm_nt(
    const float* __restrict__ A, int lda,
    const float* __restrict__ W, int ldw,
    const float* __restrict__ bias,
    float* __restrict__ C, int ldc, int M, int N, int Kdim)
{
    __shared__ float As[BK][BM + 4];
    __shared__ float Ws[BK][BN + 4];
    const int tid = threadIdx.x;
    const int bm = blockIdx.y * BM;
    const int bn = blockIdx.x * BN;
    const int tx = tid & 15;
    const int ty = tid >> 4;

    float acc[4][4];
#pragma unroll
    for (int i = 0; i < 4; ++i)
#pragma unroll
        for (int j = 0; j < 4; ++j) acc[i][j] = 0.0f;

    for (int k0 = 0; k0 < Kdim; k0 += BK) {
#pragma unroll
        for (int i = 0; i < (BM * BK) / 256; ++i) {
            int linear = tid + i * 256;
            int r = linear >> 5, kk = linear & 31;
            As[kk][r] = A[(size_t)(bm + r) * lda + k0 + kk];
        }
#pragma unroll
        for (int i = 0; i < (BN * BK) / 256; ++i) {
            int linear = tid + i * 256;
            int r = linear >> 5, kk = linear & 31;
            int gcol = bn + r;
            Ws[kk][r] = (gcol < N) ? W[(size_t)gcol * ldw + k0 + kk] : 0.0f;
        }
        __syncthreads();
#pragma unroll
        for (int kk = 0; kk < BK; ++kk) {
            float4 a4 = *(const float4*)&As[kk][ty * 4];
            float4 b4 = *(const float4*)&Ws[kk][tx * 4];
            float av[4] = {a4.x, a4.y, a4.z, a4.w};
            float bv[4] = {b4.x, b4.y, b4.z, b4.w};
#pragma unroll
            for (int i = 0; i < 4; ++i)
#pragma unroll
                for (int j = 0; j < 4; ++j)
                    acc[i][j] = fmaf(av[i], bv[j], acc[i][j]);
        }
        __syncthreads();
    }
#pragma unroll
    for (int i = 0; i < 4; ++i) {
        int row = bm + ty * 4 + i;
#pragma unroll
        for (int j = 0; j < 4; ++j) {
            int col = bn + tx * 4 + j;
            if (col < N) {
                float v = acc[i][j] + bias[col];
                if (MODE == 2) v = fmaxf(v, 0.0f);
                if (MODE == 3) v = sigf(v);
                C[(size_t)row * ldc + col] = v;
            }
        }
    }
}

// ---------------------------------------------------------------------------
// Cell update: reads g (single buffer), applies bias + time*tcoef, gates,
// c/h update, distance, sliding-window and next-step A writes.
// ---------------------------------------------------------------------------
__global__ __launch_bounds__(256) void cell_kernel(
    const float* __restrict__ g,     // [B, GP]
    const float* __restrict__ x,     // [B, T, D]
    const float* __restrict__ timep, // [B, T]
    const float* __restrict__ biasb, const float* __restrict__ tcoef,
    float* __restrict__ cbuf, float* __restrict__ hbuf,
    float* __restrict__ hwin, __hip_bfloat16* __restrict__ Ab,
    float* __restrict__ dist_out, int tstep)
{
    int b = blockIdx.x;
    const float* gr = g + (size_t)b * GP;
    const float tv = timep[(size_t)b * TT + tstep];

    float fv[LL], iv[LL];
    float mf = -1e30f, mi = -1e30f;
#pragma unroll
    for (int l = 0; l < LL; ++l) {
        fv[l] = gr[l] + biasb[l] + tv * tcoef[l];
        mf = fmaxf(mf, fv[l]);
        iv[l] = gr[LL + l] + biasb[LL + l] + tv * tcoef[LL + l];
        mi = fmaxf(mi, iv[l]);
    }
    float sf = 0.0f, si = 0.0f;
#pragma unroll
    for (int l = 0; l < LL; ++l) {
        fv[l] = expf(fv[l] - mf); sf += fv[l];
        iv[l] = expf(iv[l] - mi); si += iv[l];
    }
    float fm[LL], im[LL];
    float run = 0.0f;
#pragma unroll
    for (int l = 0; l < LL; ++l) { run += fv[l] / sf; fm[l] = run; }
    run = 0.0f;
#pragma unroll
    for (int l = LL - 1; l >= 0; --l) { run += iv[l] / si; im[l] = run; }
    float dist = 1.0f - (fm[0] + fm[1] + fm[2] + fm[3] + fm[4] + fm[5]) * (1.0f / 6.0f);

    int slot = tstep % KCONV;
    float* hw = hwin + (size_t)slot * BATCH * HH + (size_t)b * HH;

#pragma unroll
    for (int j = 0; j < 3; ++j) {
        int e = threadIdx.x + j * 256;
        int l = e >> 7;
        int c0 = 2 * LL + e;
        int c1 = c0 + HH, c2 = c1 + HH, c3 = c2 + HH;
        float fg = sigf(gr[c0] + biasb[c0] + tv * tcoef[c0]);
        float ig = sigf(gr[c1] + biasb[c1] + tv * tcoef[c1]);
        float og = sigf(gr[c2] + biasb[c2] + tv * tcoef[c2]);
        float ci = tanhf(gr[c3] + biasb[c3] + tv * tcoef[c3]);
        float cl = cbuf[(size_t)b * HH + e];
        float fmv = fm[l], imv = im[l];
        float ov = fmv * imv;
        float cn = ov * (fg * cl + ig * ci) + (fmv - ov) * cl + (imv - ov) * ci;
        float hn = og * tanhf(cn);
        cbuf[(size_t)b * HH + e] = cn;
        hbuf[(size_t)b * HH + e] = hn;
        hw[e] = hn;
        Ab[(size_t)b * KPACK + DD + e] = __hip_bfloat16(hn);
    }
    if (tstep + 1 < TT)
        Ab[(size_t)b * KPACK + threadIdx.x] =
            __hip_bfloat16(x[((size_t)b * TT + tstep + 1) * DD + threadIdx.x]);
    if (threadIdx.x == 0) dist_out[(size_t)tstep * BATCH + b] = dist;
}

// ---------------------------------------------------------------------------
__global__ __launch_bounds__(256) void window_kernel(
    const float* __restrict__ dist_out, float* __restrict__ ld)
{
    int b = blockIdx.x * blockDim.x + threadIdx.x;
    if (b >= BATCH) return;
    float w[KCONV];
    float run = 0.0f, m = -1e30f;
#pragma unroll
    for (int k = 0; k < KCONV; ++k) {
        run += dist_out[(size_t)(TT - KCONV + k) * BATCH + b];
        w[k] = run;
        m = fmaxf(m, run);
    }
    float s = 0.0f;
#pragma unroll
    for (int k = 0; k < KCONV; ++k) { w[k] = expf(w[k] - m); s += w[k]; }
    float inv = 1.0f / s;
#pragma unroll
    for (int k = 0; k < KCONV; ++k) ld[b * KCONV + k] = w[k] * inv;
}

__global__ __launch_bounds__(256) void localh_kernel(
    const float* __restrict__ hwin, const float* __restrict__ ld,
    __hip_bfloat16* __restrict__ Lhb, float* __restrict__ mh)
{
    int idx = blockIdx.x * 256 + threadIdx.x;
    int b = idx / HH;
    int e = idx - b * HH;
    float lv[KCONV];
#pragma unroll
    for (int k = 0; k < KCONV; ++k) lv[k] = ld[b * KCONV + k];
    float sum = 0.0f;
#pragma unroll
    for (int k = 0; k < KCONV; ++k) {
        int slot = (TT - KCONV + k) % KCONV;
        float v = hwin[(size_t)slot * BATCH * HH + (size_t)b * HH + e] * lv[k];
        Lhb[(size_t)b * (HH * KCONV) + e * KCONV + k] = __hip_bfloat16(v);
        sum += v;
    }
    mh[idx] = sum * (1.0f / KCONV);
}

// output[b] = sigmoid( sum_e (theme*(sum_z convp_z + conv_b) + h_last)*out_w + out_b )
__global__ __launch_bounds__(256) void out_kernel(
    const float* __restrict__ theme, const float* __restrict__ convp, size_t cstride,
    const float* __restrict__ conv_b, const float* __restrict__ hbuf,
    const float* __restrict__ out_w, const float* __restrict__ out_b,
    float* __restrict__ out)
{
    __shared__ float red[256];
    int b = blockIdx.x;
    float p = 0.0f;
    for (int e = threadIdx.x; e < HH; e += 256) {
        float cv = conv_b[e];
#pragma unroll
        for (int zz = 0; zz < 2; ++zz)
            cv += convp[(size_t)zz * cstride + (size_t)b * HH + e];
        p += (theme[(size_t)b * HH + e] * cv + hbuf[(size_t)b * HH + e]) * out_w[e];
    }
    red[threadIdx.x] = p;
    __syncthreads();
    for (int s = 128; s > 0; s >>= 1) {
        if (threadIdx.x < s) red[threadIdx.x] += red[threadIdx.x + s];
        __syncthreads();
    }
    if (threadIdx.x == 0) out[b] = sigf(red[0] + out_b[0]);
}

// ---------------------------------------------------------------------------
extern "C" void kernel_launch(void* const* d_in, const int* in_sizes, int n_in,
                              void* d_out, int out_size, void* d_ws, size_t ws_size,
                              hipStream_t stream)
{
    const float* x       = (const float*)d_in[0];
    const float* timep   = (const float*)d_in[1];
    const float* kw      = (const float*)d_in[2];
    const float* kb      = (const float*)d_in[3];
    const float* rw      = (const float*)d_in[4];
    const float* rb      = (const float*)d_in[5];
    const float* scale_w = (const float*)d_in[6];
    const float* scale_b = (const float*)d_in[7];
    const float* resc_w  = (const float*)d_in[8];
    const float* resc_b  = (const float*)d_in[9];
    const float* conv_w  = (const float*)d_in[10];
    const float* conv_b  = (const float*)d_in[11];
    const float* out_w   = (const float*)d_in[12];
    const float* out_b   = (const float*)d_in[13];

    float* outp  = (float*)d_out;
    float* distp = outp + BATCH;

    char* cur = (char*)d_ws;
    auto carve = [&](size_t bytes) {
        char* p = cur;
        cur += (bytes + 255) & ~(size_t)255;
        return (void*)p;
    };
    __hip_bfloat16* Wpb    = (__hip_bfloat16*)carve((size_t)GP * KPACK * 2);
    __hip_bfloat16* Ab     = (__hip_bfloat16*)carve((size_t)BATCH * KPACK * 2);
    __hip_bfloat16* Lhb    = (__hip_bfloat16*)carve((size_t)BATCH * HH * KCONV * 2);
    __hip_bfloat16* convwb = (__hip_bfloat16*)carve((size_t)HH * HH * KCONV * 2);
    float* tcoef = (float*)carve(GDIM * 4);
    float* biasb = (float*)carve(GDIM * 4);
    float* g     = (float*)carve((size_t)BATCH * GP * 4);
    float* hbuf  = (float*)carve((size_t)BATCH * HH * 4);
    float* cbuf  = (float*)carve((size_t)BATCH * HH * 4);
    float* hwin  = (float*)carve((size_t)KCONV * BATCH * HH * 4);
    float* ld    = (float*)carve((size_t)BATCH * KCONV * 4);
    float* mh    = (float*)carve((size_t)BATCH * HH * 4);
    float* s1    = (float*)carve((size_t)BATCH * CHW * 4);
    float* theme = (float*)carve((size_t)BATCH * HH * 4);
    float* convp = (float*)carve(2 * (size_t)BATCH * HH * 4);      // 2 conv partials

    hipMemsetAsync(hbuf, 0, 2 * (size_t)BATCH * HH * sizeof(float), stream);
    prep_kernel<<<GP, 256, 0, stream>>>(kw, kb, rw, rb, Wpb, tcoef, biasb);
    cvt_kernel<<<(HH * HH * KCONV + 255) / 256, 256, 0, stream>>>(
        conv_w, convwb, HH * HH * KCONV);
    init_ab<<<BATCH, 256, 0, stream>>>(x, Ab);

    for (int t = 0; t < TT; ++t) {
        gemm_mfma<1><<<16 * 25, 256, 0, stream>>>(
            Ab, KPACK, Wpb, KPACK, g, GP, 0, KPACK, 16, 25);
        cell_kernel<<<BATCH, 256, 0, stream>>>(
            g, x, timep, biasb, tcoef, cbuf, hbuf, hwin, Ab, distp, t);
    }

    window_kernel<<<(BATCH + 255) / 256, 256, 0, stream>>>(distp, ld);
    localh_kernel<<<(BATCH * HH) / 256, 256, 0, stream>>>(hwin, ld, Lhb, mh);

    // conv einsum: [B,7680]bf16 x [768,7680]bf16^T, K-split x2
    gemm_mfma<2><<<16 * 6 * 2, 256, 0, stream>>>(
        Lhb, HH * KCONV, convwb, HH * KCONV, convp, HH, (size_t)BATCH * HH,
        HH * KCONV, 16, 6);
    // scale (relu): [B,768] x [128,768]^T
    gemm_nt<2><<<dim3(CHW / BN, BATCH / BM), 256, 0, stream>>>(
        mh, HH, scale_w, HH, scale_b, s1, CHW, BATCH, CHW, HH);
    // rescale (sigmoid): [B,128] x [768,128]^T
    gemm_nt<3><<<dim3(HH / BN, BATCH / BM), 256, 0, stream>>>(
        s1, CHW, resc_w, CHW, resc_b, theme, HH, BATCH, HH, CHW);

    out_kernel<<<BATCH, 256, 0, stream>>>(
        theme, convp, (size_t)BATCH * HH, conv_b, hbuf, out_w, out_b, outp);
}

// Round 5
// 7352.096 us; speedup vs baseline: 7.2785x; 1.0294x over previous
//
#include <hip/hip_runtime.h>
#include <hip/hip_bf16.h>
#include <math.h>

// Problem constants
#define BATCH 1024
#define TT    256
#define DD    256
#define HH    768
#define LL    6
#define KCONV 10
#define CHW   128
#define GDIM  3084
#define KPACK 1024     // D + H
#define G4    3072     // 4*H interleaved gate cols
#define BNT   192      // gate cols per block tile (48 channels x 4 gates)
#define GSTR  196      // epilogue LDS row stride (floats)

typedef __attribute__((ext_vector_type(8))) __bf16 bf16x8;
typedef __attribute__((ext_vector_type(4))) float f32x4;

__device__ __forceinline__ float sigf(float v) { return 1.0f / (1.0f + expf(-v)); }

#define SEL6(a, l) ((l)==0?a[0]:(l)==1?a[1]:(l)==2?a[2]:(l)==3?a[3]:(l)==4?a[4]:a[5])

// async global->LDS, 16B per lane; LDS dest = wave-uniform base + lane*16
__device__ __forceinline__ void gload16(const void* g, void* l) {
    __builtin_amdgcn_global_load_lds(
        (const __attribute__((address_space(1))) unsigned int*)g,
        (__attribute__((address_space(3))) unsigned int*)l, 16, 0, 0);
}

// ---------------------------------------------------------------------------
// W4[n][1024] bf16, n = 4*e + q  <->  orig gate row 2L + q*H + e
// bias4/tco4 reordered the same way.
// ---------------------------------------------------------------------------
__global__ __launch_bounds__(256) void prep_w4(
    const float* __restrict__ kw, const float* __restrict__ kb,
    const float* __restrict__ rw, const float* __restrict__ rb,
    __hip_bfloat16* __restrict__ W4, float* __restrict__ bias4, float* __restrict__ tco4)
{
    int n = blockIdx.x;                 // 0..3071
    int e = n >> 2, q = n & 3;
    int orig = 2 * LL + q * HH + e;
    int tid = threadIdx.x;
#pragma unroll
    for (int k = 0; k < 4; ++k) {
        int col = tid + k * 256;
        float v = (col < DD) ? kw[(size_t)orig * (DD + 1) + col]
                             : rw[(size_t)orig * (HH + 1) + (col - DD)];
        W4[(size_t)n * KPACK + col] = __hip_bfloat16(v);
    }
    if (tid == 0) {
        bias4[n] = kb[orig] + rb[orig];
        tco4[n]  = kw[(size_t)orig * (DD + 1) + DD] + rw[(size_t)orig * (HH + 1) + HH];
    }
}

// Masters: Wm[64][1024], rows 0..11 = orig rows 0..11, rest zero.
__global__ __launch_bounds__(256) void prep_wm(
    const float* __restrict__ kw, const float* __restrict__ kb,
    const float* __restrict__ rw, const float* __restrict__ rb,
    __hip_bfloat16* __restrict__ Wm, float* __restrict__ mbias, float* __restrict__ mtco)
{
    int j = blockIdx.x;                 // 0..63
    int tid = threadIdx.x;
#pragma unroll
    for (int k = 0; k < 4; ++k) {
        int col = tid + k * 256;
        float v = 0.0f;
        if (j < 12)
            v = (col < DD) ? kw[(size_t)j * (DD + 1) + col]
                           : rw[(size_t)j * (HH + 1) + (col - DD)];
        Wm[(size_t)j * KPACK + col] = __hip_bfloat16(v);
    }
    if (tid == 0 && j < 12) {
        mbias[j] = kb[j] + rb[j];
        mtco[j]  = kw[(size_t)j * (DD + 1) + DD] + rw[(size_t)j * (HH + 1) + HH];
    }
}

__global__ __launch_bounds__(256) void cvt_kernel(
    const float* __restrict__ src, __hip_bfloat16* __restrict__ dst, int n)
{
    int i = blockIdx.x * 256 + threadIdx.x;
    if (i < n) dst[i] = __hip_bfloat16(src[i]);
}

// Ab0 init: x part = x[:,0,:], h part = 0
__global__ __launch_bounds__(256) void init_ab(
    const float* __restrict__ x, __hip_bfloat16* __restrict__ Ab)
{
    int b = blockIdx.x, tid = threadIdx.x;
    Ab[(size_t)b * KPACK + tid] = __hip_bfloat16(x[(size_t)b * TT * DD + tid]);
#pragma unroll
    for (int j = 0; j < 3; ++j)
        Ab[(size_t)b * KPACK + DD + tid + j * 256] = __hip_bfloat16(0.0f);
}

// ---------------------------------------------------------------------------
// Fused step: GEMM (64x192 gate tile + 64x16 masters, K=1024) + cell epilogue.
// Grid 256 blocks (16 bm x 16 bn), 256 threads = 4 waves (2x2), wave 32x96.
// Reads Ab[t&1], writes h/x into Ab[(t+1)&1] (double buffer: other blocks may
// still be staging the read buffer).
// ---------------------------------------------------------------------------
__global__ __launch_bounds__(256, 1) void step_kernel(
    const __hip_bfloat16* __restrict__ AbR,
    __hip_bfloat16* __restrict__ AbW,
    const float* __restrict__ x,
    const float* __restrict__ timep,
    const __hip_bfloat16* __restrict__ W4,
    const __hip_bfloat16* __restrict__ Wm,
    const float* __restrict__ bias4, const float* __restrict__ tco4,
    const float* __restrict__ mbias, const float* __restrict__ mtco,
    float* __restrict__ cbuf,
    float* __restrict__ hwin,
    float* __restrict__ distp,
    int t)
{
    __shared__ __align__(16) char smem[56064];
    unsigned short* AsB = (unsigned short*)smem;            // [2][64*32]   8 KB
    unsigned short* BsB = (unsigned short*)(smem + 8192);   // [2][256*32] 32 KB
    float* gl    = (float*)smem;                            // 64 x GSTR (epilogue)
    float* ml    = (float*)(smem + 50176);                  // 64 x 16
    float* biasL = (float*)(smem + 54272);                  // 192
    float* tcoL  = biasL + 192;                             // 192
    float* mbL   = tcoL + 192;                              // 16
    float* mtL   = mbL + 16;                                // 16

    const int tid = threadIdx.x;
    const int bid = blockIdx.x;
    const int swz = (bid & 7) * 32 + (bid >> 3);   // XCD swizzle (256 % 8 == 0)
    const int bm = swz & 15;
    const int bn = swz >> 4;

    const int lane = tid & 63;
    const int wid  = tid >> 6;
    const int wr   = wid >> 1, wc = wid & 1;
    const int kg   = lane >> 4;
    const int r15  = lane & 15;

    if (tid < 192) { biasL[tid] = bias4[bn * BNT + tid]; tcoL[tid] = tco4[bn * BNT + tid]; }
    if (tid < 12)  { mbL[tid] = mbias[tid]; mtL[tid] = mtco[tid]; }
    __syncthreads();

    f32x4 acc[2][6], accm[2];
#pragma unroll
    for (int m = 0; m < 2; ++m) {
#pragma unroll
        for (int n = 0; n < 6; ++n) acc[m][n] = (f32x4){0.f, 0.f, 0.f, 0.f};
        accm[m] = (f32x4){0.f, 0.f, 0.f, 0.f};
    }

    const __hip_bfloat16* Asrc = AbR + (size_t)(bm * 64) * KPACK;

    // stage one BK=32 tile; global chunk pre-swizzled (involution kc ^ ((row>>1)&3))
    auto stage = [&](int buf, int k0) {
        {   // A: 64 rows x 4 chunks = 256, one per thread
            int row = tid >> 2, kc = tid & 3;
            int sw = kc ^ ((row >> 1) & 3);
            gload16(Asrc + (size_t)row * KPACK + k0 + sw * 8,
                    AsB + buf * 2048 + tid * 8);
        }
#pragma unroll
        for (int i = 0; i < 3; ++i) {   // gate rows 0..191: 768 chunks
            int c = tid + i * 256;
            int row = c >> 2, kc = c & 3;
            int sw = kc ^ ((row >> 1) & 3);
            gload16(W4 + (size_t)(bn * BNT + row) * KPACK + k0 + sw * 8,
                    BsB + buf * 8192 + c * 8);
        }
        {   // master rows 192..255 <- Wm rows 0..63
            int c = tid + 768;
            int row = c >> 2, kc = c & 3;
            int sw = kc ^ ((row >> 1) & 3);
            gload16(Wm + (size_t)(row - 192) * KPACK + k0 + sw * 8,
                    BsB + buf * 8192 + c * 8);
        }
    };

    stage(0, 0);
    int cur = 0;
    for (int it = 0; it < 32; ++it) {
        if (it + 1 < 32) {
            stage(cur ^ 1, (it + 1) * 32);
            asm volatile("s_waitcnt vmcnt(5)" ::: "memory");   // cur's 5 loads done
        } else {
            asm volatile("s_waitcnt vmcnt(0)" ::: "memory");
        }
        __builtin_amdgcn_s_barrier();

        const unsigned short* Ac = AsB + cur * 2048;
        const unsigned short* Bc = BsB + cur * 8192;
        bf16x8 af[2], bv[6], bmf;
#pragma unroll
        for (int m = 0; m < 2; ++m) {
            int ar = wr * 32 + m * 16 + r15;
            af[m] = *(const bf16x8*)&Ac[ar * 32 + ((kg ^ ((ar >> 1) & 3)) * 8)];
        }
#pragma unroll
        for (int n = 0; n < 6; ++n) {
            int br = wc * 96 + n * 16 + r15;
            bv[n] = *(const bf16x8*)&Bc[br * 32 + ((kg ^ ((br >> 1) & 3)) * 8)];
        }
        {
            int mr = 192 + r15;
            bmf = *(const bf16x8*)&Bc[mr * 32 + ((kg ^ ((mr >> 1) & 3)) * 8)];
        }
#pragma unroll
        for (int m = 0; m < 2; ++m) {
#pragma unroll
            for (int n = 0; n < 6; ++n)
                acc[m][n] = __builtin_amdgcn_mfma_f32_16x16x32_bf16(
                    af[m], bv[n], acc[m][n], 0, 0, 0);
            accm[m] = __builtin_amdgcn_mfma_f32_16x16x32_bf16(
                af[m], bmf, accm[m], 0, 0, 0);
        }
        __builtin_amdgcn_s_barrier();
        cur ^= 1;
    }

    // ---- epilogue: acc -> LDS exchange (aliases staging buffers, safe now) ----
#pragma unroll
    for (int m = 0; m < 2; ++m)
#pragma unroll
        for (int n = 0; n < 6; ++n) {
            int col = wc * 96 + n * 16 + r15;
            int rw0 = wr * 32 + m * 16 + kg * 4;
#pragma unroll
            for (int j = 0; j < 4; ++j)
                gl[(rw0 + j) * GSTR + col] = acc[m][n][j];
        }
    if (wc == 0) {
#pragma unroll
        for (int m = 0; m < 2; ++m) {
            int rw0 = wr * 32 + m * 16 + kg * 4;
#pragma unroll
            for (int j = 0; j < 4; ++j)
                ml[(rw0 + j) * 16 + r15] = accm[m][j];
        }
    }
    __syncthreads();

    // ---- cell: thread -> row r = tid>>2, 12 channels at (tid&3)*12 ----
    const int r  = tid >> 2;
    const int qq = tid & 3;
    const int b  = bm * 64 + r;
    const float tv = timep[(size_t)b * TT + t];

    float mv[12];
#pragma unroll
    for (int i2 = 0; i2 < 12; ++i2)
        mv[i2] = ml[r * 16 + i2] + mbL[i2] + tv * mtL[i2];

    float mxf = mv[0], mxi = mv[6];
#pragma unroll
    for (int i2 = 1; i2 < 6; ++i2) { mxf = fmaxf(mxf, mv[i2]); mxi = fmaxf(mxi, mv[6 + i2]); }
    float fr[6], ir[6];
    float sf = 0.f, si = 0.f;
#pragma unroll
    for (int i2 = 0; i2 < 6; ++i2) {
        fr[i2] = expf(mv[i2] - mxf);     sf += fr[i2];
        ir[i2] = expf(mv[6 + i2] - mxi); si += ir[i2];
    }
    float fm[6], im[6];
    float rsf = 1.0f / sf, rsi = 1.0f / si;
    fm[0] = fr[0] * rsf;
#pragma unroll
    for (int i2 = 1; i2 < 6; ++i2) fm[i2] = fm[i2 - 1] + fr[i2] * rsf;
    im[5] = ir[5] * rsi;
#pragma unroll
    for (int i2 = 4; i2 >= 0; --i2) im[i2] = im[i2 + 1] + ir[i2] * rsi;

    if (bn == 0 && qq == 0) {
        float dist = 1.0f - (fm[0] + fm[1] + fm[2] + fm[3] + fm[4] + fm[5]) * (1.0f / 6.0f);
        distp[(size_t)t * BATCH + b] = dist;
    }

    const int e0 = bn * 48 + qq * 12;
    const int l0 = e0 >> 7, l1 = (e0 + 11) >> 7;
    const float fmA = SEL6(fm, l0), imA = SEL6(im, l0);
    const float fmB = SEL6(fm, l1), imB = SEL6(im, l1);

    float* cb = cbuf + (size_t)b * HH;
    __hip_bfloat16* aw = AbW + (size_t)b * KPACK;
    const bool wh = (t >= TT - KCONV);
    float* hw = hwin + (size_t)(t % KCONV) * BATCH * HH + (size_t)b * HH;

#pragma unroll
    for (int j = 0; j < 12; ++j) {
        int el = qq * 12 + j;
        int e  = bn * 48 + el;
        f32x4 gv = *(const f32x4*)&gl[r * GSTR + el * 4];
        float fg = sigf(gv[0] + biasL[el * 4 + 0] + tv * tcoL[el * 4 + 0]);
        float ig = sigf(gv[1] + biasL[el * 4 + 1] + tv * tcoL[el * 4 + 1]);
        float og = sigf(gv[2] + biasL[el * 4 + 2] + tv * tcoL[el * 4 + 2]);
        float ci = tanhf(gv[3] + biasL[el * 4 + 3] + tv * tcoL[el * 4 + 3]);
        float cl = cb[e];
        bool hi = (e >> 7) != l0;
        float fmv = hi ? fmB : fmA;
        float imv = hi ? imB : imA;
        float ov = fmv * imv;
        float cn = ov * (fg * cl + ig * ci) + (fmv - ov) * cl + (imv - ov) * ci;
        float hn = og * tanhf(cn);
        cb[e] = cn;
        aw[DD + e] = __hip_bfloat16(hn);
        if (wh) hw[e] = hn;
    }

    // x part of next A (cols 0..255): blocks bn<8, 32 cols each
    if (bn < 8 && t + 1 < TT) {
        int col0 = bn * 32 + qq * 8;
        const float* xr = x + ((size_t)b * TT + (t + 1)) * DD + col0;
#pragma unroll
        for (int jj = 0; jj < 8; ++jj)
            aw[col0 + jj] = __hip_bfloat16(xr[jj]);
    }
}

// ---------------------------------------------------------------------------
// bf16 MFMA NT GEMM (round-4 version) for the conv einsum tail.
// ---------------------------------------------------------------------------
template <int SPLIT>
__global__ __launch_bounds__(256, 2) void gemm_mfma(
    const __hip_bfloat16* __restrict__ A, int lda,
    const __hip_bfloat16* __restrict__ W, int ldw,
    float* __restrict__ C, int ldc, size_t cstride, int Kdim, int nbm, int nbn)
{
    __shared__ unsigned short As[2][64 * 64];
    __shared__ unsigned short Bs[2][128 * 64];

    const int nwg = nbm * nbn * SPLIT;
    const int cpx = nwg >> 3;
    const int bid = blockIdx.x;
    const int swz = (bid & 7) * cpx + (bid >> 3);
    const int z   = swz % SPLIT;
    const int t2  = swz / SPLIT;
    const int bm  = t2 % nbm;
    const int bn  = t2 / nbm;
    const int kspan = Kdim / SPLIT;

    const int tid  = threadIdx.x;
    const int lane = tid & 63;
    const int wid  = tid >> 6;
    const int wr   = wid >> 1, wc = wid & 1;
    const int kg   = lane >> 4;
    const int r15  = lane & 15;

    f32x4 acc[2][4];
#pragma unroll
    for (int m = 0; m < 2; ++m)
#pragma unroll
        for (int n = 0; n < 4; ++n) acc[m][n] = (f32x4){0.f, 0.f, 0.f, 0.f};

    const __hip_bfloat16* Abase = A + (size_t)(bm * 64) * lda + (size_t)z * kspan;
    const __hip_bfloat16* Wbase = W + (size_t)(bn * 128) * ldw + (size_t)z * kspan;

    auto stage = [&](int buf, int k0) {
        unsigned short* Ad = &As[buf][0];
        unsigned short* Bd = &Bs[buf][0];
#pragma unroll
        for (int i = 0; i < 2; ++i) {
            int c = tid + i * 256;
            int row = c >> 3, kc = c & 7;
            gload16(Abase + (size_t)row * lda + k0 + ((kc ^ (row & 7)) * 8), Ad + c * 8);
        }
#pragma unroll
        for (int i = 0; i < 4; ++i) {
            int c = tid + i * 256;
            int row = c >> 3, kc = c & 7;
            gload16(Wbase + (size_t)row * ldw + k0 + ((kc ^ (row & 7)) * 8), Bd + c * 8);
        }
    };

    const int NIT = kspan / 64;
    stage(0, 0);
    int cur = 0;
    for (int it = 0; it < NIT; ++it) {
        if (it + 1 < NIT) {
            stage(cur ^ 1, (it + 1) * 64);
            asm volatile("s_waitcnt vmcnt(6)" ::: "memory");
        } else {
            asm volatile("s_waitcnt vmcnt(0)" ::: "memory");
        }
        __builtin_amdgcn_s_barrier();

#pragma unroll
        for (int ks = 0; ks < 2; ++ks) {
            const int kb = ks * 4 + kg;
            bf16x8 af[2], bv[4];
#pragma unroll
            for (int m = 0; m < 2; ++m) {
                int ar = wr * 32 + m * 16 + r15;
                af[m] = *(const bf16x8*)&As[cur][ar * 64 + ((kb ^ (ar & 7)) * 8)];
            }
#pragma unroll
            for (int n = 0; n < 4; ++n) {
                int br = wc * 64 + n * 16 + r15;
                bv[n] = *(const bf16x8*)&Bs[cur][br * 64 + ((kb ^ (br & 7)) * 8)];
            }
#pragma unroll
            for (int m = 0; m < 2; ++m)
#pragma unroll
                for (int n = 0; n < 4; ++n)
                    acc[m][n] = __builtin_amdgcn_mfma_f32_16x16x32_bf16(
                        af[m], bv[n], acc[m][n], 0, 0, 0);
        }
        __builtin_amdgcn_s_barrier();
        cur ^= 1;
    }

    float* Cp = C + (size_t)z * cstride;
    const int crow0 = bm * 64 + wr * 32 + (lane >> 4) * 4;
    const int ccol0 = bn * 128 + wc * 64 + r15;
#pragma unroll
    for (int m = 0; m < 2; ++m)
#pragma unroll
        for (int n = 0; n < 4; ++n)
#pragma unroll
            for (int j = 0; j < 4; ++j)
                Cp[(size_t)(crow0 + m * 16 + j) * ldc + ccol0 + n * 16] = acc[m][n][j];
}

// ---------------------------------------------------------------------------
// fp32 NT GEMM for the tiny tail matmuls. MODE 2: relu ; MODE 3: sigmoid
// ---------------------------------------------------------------------------
#define BM 64
#define BN 64
#define BK 32
template <int MODE>
__global__ __launch_bounds__(256) void gemm_nt(
    const float* __restrict__ A, int lda,
    const float* __restrict__ W, int ldw,
    const float* __restrict__ bias,
    float* __restrict__ C, int ldc, int M, int N, int Kdim)
{
    __shared__ float As[BK][BM + 4];
    __shared__ float Ws[BK][BN + 4];
    const int tid = threadIdx.x;
    const int bm = blockIdx.y * BM;
    const int bn = blockIdx.x * BN;
    const int tx = tid & 15;
    const int ty = tid >> 4;

    float acc[4][4];
#pragma unroll
    for (int i = 0; i < 4; ++i)
#pragma unroll
        for (int j = 0; j < 4; ++j) acc[i][j] = 0.0f;

    for (int k0 = 0; k0 < Kdim; k0 += BK) {
#pragma unroll
        for (int i = 0; i < (BM * BK) / 256; ++i) {
            int linear = tid + i * 256;
            int r = linear >> 5, kk = linear & 31;
            As[kk][r] = A[(size_t)(bm + r) * lda + k0 + kk];
        }
#pragma unroll
        for (int i = 0; i < (BN * BK) / 256; ++i) {
            int linear = tid + i * 256;
            int r = linear >> 5, kk = linear & 31;
            int gcol = bn + r;
            Ws[kk][r] = (gcol < N) ? W[(size_t)gcol * ldw + k0 + kk] : 0.0f;
        }
        __syncthreads();
#pragma unroll
        for (int kk = 0; kk < BK; ++kk) {
            float4 a4 = *(const float4*)&As[kk][ty * 4];
            float4 b4 = *(const float4*)&Ws[kk][tx * 4];
            float av[4] = {a4.x, a4.y, a4.z, a4.w};
            float bv[4] = {b4.x, b4.y, b4.z, b4.w};
#pragma unroll
            for (int i = 0; i < 4; ++i)
#pragma unroll
                for (int j = 0; j < 4; ++j)
                    acc[i][j] = fmaf(av[i], bv[j], acc[i][j]);
        }
        __syncthreads();
    }
#pragma unroll
    for (int i = 0; i < 4; ++i) {
        int row = bm + ty * 4 + i;
#pragma unroll
        for (int j = 0; j < 4; ++j) {
            int col = bn + tx * 4 + j;
            if (col < N) {
                float v = acc[i][j] + bias[col];
                if (MODE == 2) v = fmaxf(v, 0.0f);
                if (MODE == 3) v = sigf(v);
                C[(size_t)row * ldc + col] = v;
            }
        }
    }
}

// ---------------------------------------------------------------------------
__global__ __launch_bounds__(256) void window_kernel(
    const float* __restrict__ dist_out, float* __restrict__ ld)
{
    int b = blockIdx.x * blockDim.x + threadIdx.x;
    if (b >= BATCH) return;
    float w[KCONV];
    float run = 0.0f, m = -1e30f;
#pragma unroll
    for (int k = 0; k < KCONV; ++k) {
        run += dist_out[(size_t)(TT - KCONV + k) * BATCH + b];
        w[k] = run;
        m = fmaxf(m, run);
    }
    float s = 0.0f;
#pragma unroll
    for (int k = 0; k < KCONV; ++k) { w[k] = expf(w[k] - m); s += w[k]; }
    float inv = 1.0f / s;
#pragma unroll
    for (int k = 0; k < KCONV; ++k) ld[b * KCONV + k] = w[k] * inv;
}

__global__ __launch_bounds__(256) void localh_kernel(
    const float* __restrict__ hwin, const float* __restrict__ ld,
    __hip_bfloat16* __restrict__ Lhb, float* __restrict__ mh)
{
    int idx = blockIdx.x * 256 + threadIdx.x;
    int b = idx / HH;
    int e = idx - b * HH;
    float lv[KCONV];
#pragma unroll
    for (int k = 0; k < KCONV; ++k) lv[k] = ld[b * KCONV + k];
    float sum = 0.0f;
#pragma unroll
    for (int k = 0; k < KCONV; ++k) {
        int slot = (TT - KCONV + k) % KCONV;
        float v = hwin[(size_t)slot * BATCH * HH + (size_t)b * HH + e] * lv[k];
        Lhb[(size_t)b * (HH * KCONV) + e * KCONV + k] = __hip_bfloat16(v);
        sum += v;
    }
    mh[idx] = sum * (1.0f / KCONV);
}

__global__ __launch_bounds__(256) void out_kernel(
    const float* __restrict__ theme, const float* __restrict__ convp, size_t cstride,
    const float* __restrict__ conv_b, const float* __restrict__ hbuf,
    const float* __restrict__ out_w, const float* __restrict__ out_b,
    float* __restrict__ out)
{
    __shared__ float red[256];
    int b = blockIdx.x;
    float p = 0.0f;
    for (int e = threadIdx.x; e < HH; e += 256) {
        float cv = conv_b[e];
#pragma unroll
        for (int zz = 0; zz < 2; ++zz)
            cv += convp[(size_t)zz * cstride + (size_t)b * HH + e];
        p += (theme[(size_t)b * HH + e] * cv + hbuf[(size_t)b * HH + e]) * out_w[e];
    }
    red[threadIdx.x] = p;
    __syncthreads();
    for (int s = 128; s > 0; s >>= 1) {
        if (threadIdx.x < s) red[threadIdx.x] += red[threadIdx.x + s];
        __syncthreads();
    }
    if (threadIdx.x == 0) out[b] = sigf(red[0] + out_b[0]);
}

// ---------------------------------------------------------------------------
extern "C" void kernel_launch(void* const* d_in, const int* in_sizes, int n_in,
                              void* d_out, int out_size, void* d_ws, size_t ws_size,
                              hipStream_t stream)
{
    const float* x       = (const float*)d_in[0];
    const float* timep   = (const float*)d_in[1];
    const float* kw      = (const float*)d_in[2];
    const float* kb      = (const float*)d_in[3];
    const float* rw      = (const float*)d_in[4];
    const float* rb      = (const float*)d_in[5];
    const float* scale_w = (const float*)d_in[6];
    const float* scale_b = (const float*)d_in[7];
    const float* resc_w  = (const float*)d_in[8];
    const float* resc_b  = (const float*)d_in[9];
    const float* conv_w  = (const float*)d_in[10];
    const float* conv_b  = (const float*)d_in[11];
    const float* out_w   = (const float*)d_in[12];
    const float* out_b   = (const float*)d_in[13];

    float* outp  = (float*)d_out;
    float* distp = outp + BATCH;

    char* cur = (char*)d_ws;
    auto carve = [&](size_t bytes) {
        char* p = cur;
        cur += (bytes + 255) & ~(size_t)255;
        return (void*)p;
    };
    __hip_bfloat16* W4     = (__hip_bfloat16*)carve((size_t)G4 * KPACK * 2);
    __hip_bfloat16* Wm     = (__hip_bfloat16*)carve((size_t)64 * KPACK * 2);
    __hip_bfloat16* Ab0    = (__hip_bfloat16*)carve((size_t)BATCH * KPACK * 2);
    __hip_bfloat16* Ab1    = (__hip_bfloat16*)carve((size_t)BATCH * KPACK * 2);
    __hip_bfloat16* Lhb    = (__hip_bfloat16*)carve((size_t)BATCH * HH * KCONV * 2);
    __hip_bfloat16* convwb = (__hip_bfloat16*)carve((size_t)HH * HH * KCONV * 2);
    float* bias4 = (float*)carve(G4 * 4);
    float* tco4  = (float*)carve(G4 * 4);
    float* mbias = (float*)carve(64);
    float* mtco  = (float*)carve(64);
    float* cbuf  = (float*)carve((size_t)BATCH * HH * 4);
    float* hwin  = (float*)carve((size_t)KCONV * BATCH * HH * 4);
    float* ld    = (float*)carve((size_t)BATCH * KCONV * 4);
    float* mh    = (float*)carve((size_t)BATCH * HH * 4);
    float* s1    = (float*)carve((size_t)BATCH * CHW * 4);
    float* theme = (float*)carve((size_t)BATCH * HH * 4);
    float* convp = (float*)carve(2 * (size_t)BATCH * HH * 4);

    hipMemsetAsync(cbuf, 0, (size_t)BATCH * HH * sizeof(float), stream);
    prep_w4<<<G4, 256, 0, stream>>>(kw, kb, rw, rb, W4, bias4, tco4);
    prep_wm<<<64, 256, 0, stream>>>(kw, kb, rw, rb, Wm, mbias, mtco);
    cvt_kernel<<<(HH * HH * KCONV + 255) / 256, 256, 0, stream>>>(
        conv_w, convwb, HH * HH * KCONV);
    init_ab<<<BATCH, 256, 0, stream>>>(x, Ab0);

    for (int t = 0; t < TT; ++t) {
        const __hip_bfloat16* AbR = (t & 1) ? Ab1 : Ab0;
        __hip_bfloat16*       AbW = (t & 1) ? Ab0 : Ab1;
        step_kernel<<<256, 256, 0, stream>>>(
            AbR, AbW, x, timep, W4, Wm, bias4, tco4, mbias, mtco,
            cbuf, hwin, distp, t);
    }

    window_kernel<<<(BATCH + 255) / 256, 256, 0, stream>>>(distp, ld);
    localh_kernel<<<(BATCH * HH) / 256, 256, 0, stream>>>(hwin, ld, Lhb, mh);

    // conv einsum: [B,7680]bf16 x [768,7680]bf16^T, K-split x2
    gemm_mfma<2><<<16 * 6 * 2, 256, 0, stream>>>(
        Lhb, HH * KCONV, convwb, HH * KCONV, convp, HH, (size_t)BATCH * HH,
        HH * KCONV, 16, 6);
    // scale (relu): [B,768] x [128,768]^T
    gemm_nt<2><<<dim3(CHW / BN, BATCH / BM), 256, 0, stream>>>(
        mh, HH, scale_w, HH, scale_b, s1, CHW, BATCH, CHW, HH);
    // rescale (sigmoid): [B,128] x [768,128]^T
    gemm_nt<3><<<dim3(HH / BN, BATCH / BM), 256, 0, stream>>>(
        s1, CHW, resc_w, CHW, resc_b, theme, HH, BATCH, HH, CHW);

    out_kernel<<<BATCH, 256, 0, stream>>>(
        theme, convp, (size_t)BATCH * HH, conv_b,
        hwin + (size_t)((TT - 1) % KCONV) * BATCH * HH,   // h_last
        out_w, out_b, outp);
}

// Round 6
// 6353.318 us; speedup vs baseline: 8.4227x; 1.1572x over previous
//
#include <hip/hip_runtime.h>
#include <hip/hip_bf16.h>
#include <math.h>

// Problem constants
#define BATCH 1024
#define TT    256
#define DD    256
#define HH    768
#define LL    6
#define KCONV 10
#define CHW   128
#define GDIM  3084
#define KPACK 1024     // D + H
#define G4    3072     // 4*H interleaved gate cols
#define BNT   192      // gate cols per block tile (48 channels x 4 gates)
#define GSTR  196      // epilogue LDS row stride (floats)

typedef __attribute__((ext_vector_type(8))) __bf16 bf16x8;
typedef __attribute__((ext_vector_type(4))) float f32x4;

__device__ __forceinline__ float sigf(float v) { return 1.0f / (1.0f + expf(-v)); }

#define SEL6(a, l) ((l)==0?a[0]:(l)==1?a[1]:(l)==2?a[2]:(l)==3?a[3]:(l)==4?a[4]:a[5])

// async global->LDS, 16B per lane; LDS dest = wave-uniform base + lane*16
__device__ __forceinline__ void gload16(const void* g, void* l) {
    __builtin_amdgcn_global_load_lds(
        (const __attribute__((address_space(1))) unsigned int*)g,
        (__attribute__((address_space(3))) unsigned int*)l, 16, 0, 0);
}

// ---------------------------------------------------------------------------
// W4[n][1024] bf16, n = 4*e + q  <->  orig gate row 2L + q*H + e
// ---------------------------------------------------------------------------
__global__ __launch_bounds__(256) void prep_w4(
    const float* __restrict__ kw, const float* __restrict__ kb,
    const float* __restrict__ rw, const float* __restrict__ rb,
    __hip_bfloat16* __restrict__ W4, float* __restrict__ bias4, float* __restrict__ tco4)
{
    int n = blockIdx.x;                 // 0..3071
    int e = n >> 2, q = n & 3;
    int orig = 2 * LL + q * HH + e;
    int tid = threadIdx.x;
#pragma unroll
    for (int k = 0; k < 4; ++k) {
        int col = tid + k * 256;
        float v = (col < DD) ? kw[(size_t)orig * (DD + 1) + col]
                             : rw[(size_t)orig * (HH + 1) + (col - DD)];
        W4[(size_t)n * KPACK + col] = __hip_bfloat16(v);
    }
    if (tid == 0) {
        bias4[n] = kb[orig] + rb[orig];
        tco4[n]  = kw[(size_t)orig * (DD + 1) + DD] + rw[(size_t)orig * (HH + 1) + HH];
    }
}

// Masters: Wm[16][1024], rows 0..11 = orig rows 0..11, rows 12..15 zero.
__global__ __launch_bounds__(256) void prep_wm(
    const float* __restrict__ kw, const float* __restrict__ kb,
    const float* __restrict__ rw, const float* __restrict__ rb,
    __hip_bfloat16* __restrict__ Wm, float* __restrict__ mbias, float* __restrict__ mtco)
{
    int j = blockIdx.x;                 // 0..15
    int tid = threadIdx.x;
#pragma unroll
    for (int k = 0; k < 4; ++k) {
        int col = tid + k * 256;
        float v = 0.0f;
        if (j < 12)
            v = (col < DD) ? kw[(size_t)j * (DD + 1) + col]
                           : rw[(size_t)j * (HH + 1) + (col - DD)];
        Wm[(size_t)j * KPACK + col] = __hip_bfloat16(v);
    }
    if (tid == 0 && j < 12) {
        mbias[j] = kb[j] + rb[j];
        mtco[j]  = kw[(size_t)j * (DD + 1) + DD] + rw[(size_t)j * (HH + 1) + HH];
    }
}

__global__ __launch_bounds__(256) void cvt_kernel(
    const float* __restrict__ src, __hip_bfloat16* __restrict__ dst, int n)
{
    int i = blockIdx.x * 256 + threadIdx.x;
    if (i < n) dst[i] = __hip_bfloat16(src[i]);
}

// Ab0 init: x part = x[:,0,:], h part = 0
__global__ __launch_bounds__(256) void init_ab(
    const float* __restrict__ x, __hip_bfloat16* __restrict__ Ab)
{
    int b = blockIdx.x, tid = threadIdx.x;
    Ab[(size_t)b * KPACK + tid] = __hip_bfloat16(x[(size_t)b * TT * DD + tid]);
#pragma unroll
    for (int j = 0; j < 3; ++j)
        Ab[(size_t)b * KPACK + DD + tid + j * 256] = __hip_bfloat16(0.0f);
}

// ---------------------------------------------------------------------------
// Fused step: GEMM (64x192 gate tile + 64x16 masters, K=1024) + cell epilogue.
// Grid 256 blocks (16 bm x 16 bn), 512 threads = 8 waves (2x4), wave 32x48;
// master columns handled by waves wid==3 (rows 0..31) and wid==4 (rows 32..63).
// 2 waves/SIMD for latency hiding. Reads Ab[t&1], writes Ab[(t+1)&1].
// ---------------------------------------------------------------------------
__global__ __launch_bounds__(512, 2) void step_kernel(
    const __hip_bfloat16* __restrict__ AbR,
    __hip_bfloat16* __restrict__ AbW,
    const float* __restrict__ x,
    const float* __restrict__ timep,
    const __hip_bfloat16* __restrict__ W4,
    const __hip_bfloat16* __restrict__ Wm,
    const float* __restrict__ bias4, const float* __restrict__ tco4,
    const float* __restrict__ mbias, const float* __restrict__ mtco,
    float* __restrict__ cbuf,
    float* __restrict__ hwin,
    float* __restrict__ distp,
    int t)
{
    // arena: staging [A0 4K][A1 4K][B0 13312][B1 13312] = 34816 B
    //        epilogue alias: gl 64xGSTR f32 = 50176 B, ml @50176 (4 KB)
    //        bias @54272: biasL 768, tcoL 768, mbL 64, mtL 64 -> 55936 B
    __shared__ __align__(16) char smem[55936];
    unsigned short* Abase = (unsigned short*)smem;            // [2][64*32]
    unsigned short* Bbase = (unsigned short*)(smem + 8192);   // [2][208*32]
    float* gl    = (float*)smem;                              // 64 x GSTR
    float* ml    = (float*)(smem + 50176);                    // 64 x 16
    float* biasL = (float*)(smem + 54272);                    // 192
    float* tcoL  = biasL + 192;                               // 192
    float* mbL   = tcoL + 192;                                // 16
    float* mtL   = mbL + 16;                                  // 16

    const int tid = threadIdx.x;
    const int bid = blockIdx.x;
    const int swz = (bid & 7) * 32 + (bid >> 3);   // XCD swizzle (256 % 8 == 0)
    const int bm = swz & 15;
    const int bn = swz >> 4;

    const int lane = tid & 63;
    const int wid  = tid >> 6;                     // 0..7
    const int wr   = wid >> 2, wc = wid & 3;       // 2 x 4 wave grid
    const int kg   = lane >> 4;
    const int r15  = lane & 15;
    const bool domast = (wid == 3) || (wid == 4);  // masters on SIMD 3 and 0

    if (tid < 192) { biasL[tid] = bias4[bn * BNT + tid]; tcoL[tid] = tco4[bn * BNT + tid]; }
    if (tid >= 256 && tid < 268) { mbL[tid - 256] = mbias[tid - 256]; mtL[tid - 256] = mtco[tid - 256]; }
    __syncthreads();   // drains bias loads -> clean vmcnt slate

    f32x4 acc[2][3], accm[2];
#pragma unroll
    for (int m = 0; m < 2; ++m) {
#pragma unroll
        for (int n = 0; n < 3; ++n) acc[m][n] = (f32x4){0.f, 0.f, 0.f, 0.f};
        accm[m] = (f32x4){0.f, 0.f, 0.f, 0.f};
    }

    const __hip_bfloat16* Asrc = AbR + (size_t)(bm * 64) * KPACK;

    // 1088 16B chunks per BK=32 tile: A 256 (64 rows x 4), B 832 (208 rows x 4).
    // thread -> chunks {tid, tid+512, tid<64: 1024+tid}; involution swizzle
    // kc ^= (row>>1)&3 applied on the GLOBAL side (LDS dest stays linear).
    auto stage_chunk = [&](int c, int buf, int k0) {
        if (c < 256) {
            int row = c >> 2, kc = c & 3;
            int sw = kc ^ ((row >> 1) & 3);
            gload16(Asrc + (size_t)row * KPACK + k0 + sw * 8,
                    Abase + buf * 2048 + c * 8);
        } else {
            int cb = c - 256;
            int row = cb >> 2, kc = cb & 3;
            int sw = kc ^ ((row >> 1) & 3);
            const __hip_bfloat16* src = (row < BNT)
                ? W4 + (size_t)(bn * BNT + row) * KPACK
                : Wm + (size_t)(row - BNT) * KPACK;
            gload16(src + k0 + sw * 8, Bbase + buf * 6656 + cb * 8);
        }
    };
    auto stage = [&](int buf, int k0) {
        stage_chunk(tid, buf, k0);
        stage_chunk(tid + 512, buf, k0);
        if (tid < 64) stage_chunk(1024 + tid, buf, k0);
    };

    stage(0, 0);
    int cur = 0;
    for (int it = 0; it < 32; ++it) {
        if (it + 1 < 32) {
            stage(cur ^ 1, (it + 1) * 32);
            if (wid == 0) asm volatile("s_waitcnt vmcnt(3)" ::: "memory");
            else          asm volatile("s_waitcnt vmcnt(2)" ::: "memory");
        } else {
            asm volatile("s_waitcnt vmcnt(0)" ::: "memory");
        }
        __builtin_amdgcn_s_barrier();

        const unsigned short* Ac = Abase + cur * 2048;
        const unsigned short* Bc = Bbase + cur * 6656;
        bf16x8 af[2], bv[3];
#pragma unroll
        for (int m = 0; m < 2; ++m) {
            int ar = wr * 32 + m * 16 + r15;
            af[m] = *(const bf16x8*)&Ac[ar * 32 + ((kg ^ ((ar >> 1) & 3)) * 8)];
        }
#pragma unroll
        for (int n = 0; n < 3; ++n) {
            int br = wc * 48 + n * 16 + r15;
            bv[n] = *(const bf16x8*)&Bc[br * 32 + ((kg ^ ((br >> 1) & 3)) * 8)];
        }
#pragma unroll
        for (int m = 0; m < 2; ++m)
#pragma unroll
            for (int n = 0; n < 3; ++n)
                acc[m][n] = __builtin_amdgcn_mfma_f32_16x16x32_bf16(
                    af[m], bv[n], acc[m][n], 0, 0, 0);
        if (domast) {
            int mr = BNT + r15;   // rows 192..207
            bf16x8 bmf = *(const bf16x8*)&Bc[mr * 32 + ((kg ^ ((mr >> 1) & 3)) * 8)];
#pragma unroll
            for (int m = 0; m < 2; ++m)
                accm[m] = __builtin_amdgcn_mfma_f32_16x16x32_bf16(
                    af[m], bmf, accm[m], 0, 0, 0);
        }
        __builtin_amdgcn_s_barrier();
        cur ^= 1;
    }

    // ---- epilogue: acc -> LDS exchange (aliases staging buffers, safe now) ----
#pragma unroll
    for (int m = 0; m < 2; ++m)
#pragma unroll
        for (int n = 0; n < 3; ++n) {
            int col = wc * 48 + n * 16 + r15;
            int rw0 = wr * 32 + m * 16 + kg * 4;
#pragma unroll
            for (int j = 0; j < 4; ++j)
                gl[(rw0 + j) * GSTR + col] = acc[m][n][j];
        }
    if (domast) {
#pragma unroll
        for (int m = 0; m < 2; ++m) {
            int rw0 = wr * 32 + m * 16 + kg * 4;
#pragma unroll
            for (int j = 0; j < 4; ++j)
                ml[(rw0 + j) * 16 + r15] = accm[m][j];
        }
    }
    __syncthreads();

    // ---- cell: thread -> row r = tid>>3, 6 channels at (tid&7)*6 ----
    const int r  = tid >> 3;
    const int qq = tid & 7;
    const int b  = bm * 64 + r;
    const float tv = timep[(size_t)b * TT + t];

    float mv[12];
#pragma unroll
    for (int i2 = 0; i2 < 12; ++i2)
        mv[i2] = ml[r * 16 + i2] + mbL[i2] + tv * mtL[i2];

    float mxf = mv[0], mxi = mv[6];
#pragma unroll
    for (int i2 = 1; i2 < 6; ++i2) { mxf = fmaxf(mxf, mv[i2]); mxi = fmaxf(mxi, mv[6 + i2]); }
    float fr[6], ir[6];
    float sf = 0.f, si = 0.f;
#pragma unroll
    for (int i2 = 0; i2 < 6; ++i2) {
        fr[i2] = expf(mv[i2] - mxf);     sf += fr[i2];
        ir[i2] = expf(mv[6 + i2] - mxi); si += ir[i2];
    }
    float fm[6], im[6];
    float rsf = 1.0f / sf, rsi = 1.0f / si;
    fm[0] = fr[0] * rsf;
#pragma unroll
    for (int i2 = 1; i2 < 6; ++i2) fm[i2] = fm[i2 - 1] + fr[i2] * rsf;
    im[5] = ir[5] * rsi;
#pragma unroll
    for (int i2 = 4; i2 >= 0; --i2) im[i2] = im[i2 + 1] + ir[i2] * rsi;

    if (bn == 0 && qq == 0) {
        float dist = 1.0f - (fm[0] + fm[1] + fm[2] + fm[3] + fm[4] + fm[5]) * (1.0f / 6.0f);
        distp[(size_t)t * BATCH + b] = dist;
    }

    const int e0 = bn * 48 + qq * 6;
    const int l0 = e0 >> 7, l1 = (e0 + 5) >> 7;
    const float fmA = SEL6(fm, l0), imA = SEL6(im, l0);
    const float fmB = SEL6(fm, l1), imB = SEL6(im, l1);

    float* cb = cbuf + (size_t)b * HH;
    __hip_bfloat16* aw = AbW + (size_t)b * KPACK;
    const bool wh = (t >= TT - KCONV);
    float* hw = hwin + (size_t)(t % KCONV) * BATCH * HH + (size_t)b * HH;

#pragma unroll
    for (int j = 0; j < 6; ++j) {
        int el = qq * 6 + j;
        int e  = bn * 48 + el;
        f32x4 gv = *(const f32x4*)&gl[r * GSTR + el * 4];
        float fg = sigf(gv[0] + biasL[el * 4 + 0] + tv * tcoL[el * 4 + 0]);
        float ig = sigf(gv[1] + biasL[el * 4 + 1] + tv * tcoL[el * 4 + 1]);
        float og = sigf(gv[2] + biasL[el * 4 + 2] + tv * tcoL[el * 4 + 2]);
        float ci = tanhf(gv[3] + biasL[el * 4 + 3] + tv * tcoL[el * 4 + 3]);
        float cl = cb[e];
        bool hi = (e >> 7) != l0;
        float fmv = hi ? fmB : fmA;
        float imv = hi ? imB : imA;
        float ov = fmv * imv;
        float cn = ov * (fg * cl + ig * ci) + (fmv - ov) * cl + (imv - ov) * ci;
        float hn = og * tanhf(cn);
        cb[e] = cn;
        aw[DD + e] = __hip_bfloat16(hn);
        if (wh) hw[e] = hn;
    }

    // x part of next A (cols 0..255): blocks bn<8, 32 cols each row
    if (bn < 8 && t + 1 < TT) {
        int col0 = bn * 32 + qq * 4;
        const float* xr = x + ((size_t)b * TT + (t + 1)) * DD + col0;
#pragma unroll
        for (int jj = 0; jj < 4; ++jj)
            aw[col0 + jj] = __hip_bfloat16(xr[jj]);
    }
}

// ---------------------------------------------------------------------------
// bf16 MFMA NT GEMM for the conv einsum tail.
// ---------------------------------------------------------------------------
template <int SPLIT>
__global__ __launch_bounds__(256, 2) void gemm_mfma(
    const __hip_bfloat16* __restrict__ A, int lda,
    const __hip_bfloat16* __restrict__ W, int ldw,
    float* __restrict__ C, int ldc, size_t cstride, int Kdim, int nbm, int nbn)
{
    __shared__ unsigned short As[2][64 * 64];
    __shared__ unsigned short Bs[2][128 * 64];

    const int nwg = nbm * nbn * SPLIT;
    const int cpx = nwg >> 3;
    const int bid = blockIdx.x;
    const int swz = (bid & 7) * cpx + (bid >> 3);
    const int z   = swz % SPLIT;
    const int t2  = swz / SPLIT;
    const int bm  = t2 % nbm;
    const int bn  = t2 / nbm;
    const int kspan = Kdim / SPLIT;

    const int tid  = threadIdx.x;
    const int lane = tid & 63;
    const int wid  = tid >> 6;
    const int wr   = wid >> 1, wc = wid & 1;
    const int kg   = lane >> 4;
    const int r15  = lane & 15;

    f32x4 acc[2][4];
#pragma unroll
    for (int m = 0; m < 2; ++m)
#pragma unroll
        for (int n = 0; n < 4; ++n) acc[m][n] = (f32x4){0.f, 0.f, 0.f, 0.f};

    const __hip_bfloat16* Abase = A + (size_t)(bm * 64) * lda + (size_t)z * kspan;
    const __hip_bfloat16* Wbase = W + (size_t)(bn * 128) * ldw + (size_t)z * kspan;

    auto stage = [&](int buf, int k0) {
        unsigned short* Ad = &As[buf][0];
        unsigned short* Bd = &Bs[buf][0];
#pragma unroll
        for (int i = 0; i < 2; ++i) {
            int c = tid + i * 256;
            int row = c >> 3, kc = c & 7;
            gload16(Abase + (size_t)row * lda + k0 + ((kc ^ (row & 7)) * 8), Ad + c * 8);
        }
#pragma unroll
        for (int i = 0; i < 4; ++i) {
            int c = tid + i * 256;
            int row = c >> 3, kc = c & 7;
            gload16(Wbase + (size_t)row * ldw + k0 + ((kc ^ (row & 7)) * 8), Bd + c * 8);
        }
    };

    const int NIT = kspan / 64;
    stage(0, 0);
    int cur = 0;
    for (int it = 0; it < NIT; ++it) {
        if (it + 1 < NIT) {
            stage(cur ^ 1, (it + 1) * 64);
            asm volatile("s_waitcnt vmcnt(6)" ::: "memory");
        } else {
            asm volatile("s_waitcnt vmcnt(0)" ::: "memory");
        }
        __builtin_amdgcn_s_barrier();

#pragma unroll
        for (int ks = 0; ks < 2; ++ks) {
            const int kb = ks * 4 + kg;
            bf16x8 af[2], bv[4];
#pragma unroll
            for (int m = 0; m < 2; ++m) {
                int ar = wr * 32 + m * 16 + r15;
                af[m] = *(const bf16x8*)&As[cur][ar * 64 + ((kb ^ (ar & 7)) * 8)];
            }
#pragma unroll
            for (int n = 0; n < 4; ++n) {
                int br = wc * 64 + n * 16 + r15;
                bv[n] = *(const bf16x8*)&Bs[cur][br * 64 + ((kb ^ (br & 7)) * 8)];
            }
#pragma unroll
            for (int m = 0; m < 2; ++m)
#pragma unroll
                for (int n = 0; n < 4; ++n)
                    acc[m][n] = __builtin_amdgcn_mfma_f32_16x16x32_bf16(
                        af[m], bv[n], acc[m][n], 0, 0, 0);
        }
        __builtin_amdgcn_s_barrier();
        cur ^= 1;
    }

    float* Cp = C + (size_t)z * cstride;
    const int crow0 = bm * 64 + wr * 32 + (lane >> 4) * 4;
    const int ccol0 = bn * 128 + wc * 64 + r15;
#pragma unroll
    for (int m = 0; m < 2; ++m)
#pragma unroll
        for (int n = 0; n < 4; ++n)
#pragma unroll
            for (int j = 0; j < 4; ++j)
                Cp[(size_t)(crow0 + m * 16 + j) * ldc + ccol0 + n * 16] = acc[m][n][j];
}

// ---------------------------------------------------------------------------
// fp32 NT GEMM for the tiny tail matmuls. MODE 2: relu ; MODE 3: sigmoid
// ---------------------------------------------------------------------------
#define BM 64
#define BN 64
#define BK 32
template <int MODE>
__global__ __launch_bounds__(256) void gemm_nt(
    const float* __restrict__ A, int lda,
    const float* __restrict__ W, int ldw,
    const float* __restrict__ bias,
    float* __restrict__ C, int ldc, int M, int N, int Kdim)
{
    __shared__ float As[BK][BM + 4];
    __shared__ float Ws[BK][BN + 4];
    const int tid = threadIdx.x;
    const int bm = blockIdx.y * BM;
    const int bn = blockIdx.x * BN;
    const int tx = tid & 15;
    const int ty = tid >> 4;

    float acc[4][4];
#pragma unroll
    for (int i = 0; i < 4; ++i)
#pragma unroll
        for (int j = 0; j < 4; ++j) acc[i][j] = 0.0f;

    for (int k0 = 0; k0 < Kdim; k0 += BK) {
#pragma unroll
        for (int i = 0; i < (BM * BK) / 256; ++i) {
            int linear = tid + i * 256;
            int r = linear >> 5, kk = linear & 31;
            As[kk][r] = A[(size_t)(bm + r) * lda + k0 + kk];
        }
#pragma unroll
        for (int i = 0; i < (BN * BK) / 256; ++i) {
            int linear = tid + i * 256;
            int r = linear >> 5, kk = linear & 31;
            int gcol = bn + r;
            Ws[kk][r] = (gcol < N) ? W[(size_t)gcol * ldw + k0 + kk] : 0.0f;
        }
        __syncthreads();
#pragma unroll
        for (int kk = 0; kk < BK; ++kk) {
            float4 a4 = *(const float4*)&As[kk][ty * 4];
            float4 b4 = *(const float4*)&Ws[kk][tx * 4];
            float av[4] = {a4.x, a4.y, a4.z, a4.w};
            float bv[4] = {b4.x, b4.y, b4.z, b4.w};
#pragma unroll
            for (int i = 0; i < 4; ++i)
#pragma unroll
                for (int j = 0; j < 4; ++j)
                    acc[i][j] = fmaf(av[i], bv[j], acc[i][j]);
        }
        __syncthreads();
    }
#pragma unroll
    for (int i = 0; i < 4; ++i) {
        int row = bm + ty * 4 + i;
#pragma unroll
        for (int j = 0; j < 4; ++j) {
            int col = bn + tx * 4 + j;
            if (col < N) {
                float v = acc[i][j] + bias[col];
                if (MODE == 2) v = fmaxf(v, 0.0f);
                if (MODE == 3) v = sigf(v);
                C[(size_t)row * ldc + col] = v;
            }
        }
    }
}

// ---------------------------------------------------------------------------
__global__ __launch_bounds__(256) void window_kernel(
    const float* __restrict__ dist_out, float* __restrict__ ld)
{
    int b = blockIdx.x * blockDim.x + threadIdx.x;
    if (b >= BATCH) return;
    float w[KCONV];
    float run = 0.0f, m = -1e30f;
#pragma unroll
    for (int k = 0; k < KCONV; ++k) {
        run += dist_out[(size_t)(TT - KCONV + k) * BATCH + b];
        w[k] = run;
        m = fmaxf(m, run);
    }
    float s = 0.0f;
#pragma unroll
    for (int k = 0; k < KCONV; ++k) { w[k] = expf(w[k] - m); s += w[k]; }
    float inv = 1.0f / s;
#pragma unroll
    for (int k = 0; k < KCONV; ++k) ld[b * KCONV + k] = w[k] * inv;
}

__global__ __launch_bounds__(256) void localh_kernel(
    const float* __restrict__ hwin, const float* __restrict__ ld,
    __hip_bfloat16* __restrict__ Lhb, float* __restrict__ mh)
{
    int idx = blockIdx.x * 256 + threadIdx.x;
    int b = idx / HH;
    int e = idx - b * HH;
    float lv[KCONV];
#pragma unroll
    for (int k = 0; k < KCONV; ++k) lv[k] = ld[b * KCONV + k];
    float sum = 0.0f;
#pragma unroll
    for (int k = 0; k < KCONV; ++k) {
        int slot = (TT - KCONV + k) % KCONV;
        float v = hwin[(size_t)slot * BATCH * HH + (size_t)b * HH + e] * lv[k];
        Lhb[(size_t)b * (HH * KCONV) + e * KCONV + k] = __hip_bfloat16(v);
        sum += v;
    }
    mh[idx] = sum * (1.0f / KCONV);
}

__global__ __launch_bounds__(256) void out_kernel(
    const float* __restrict__ theme, const float* __restrict__ convp, size_t cstride,
    const float* __restrict__ conv_b, const float* __restrict__ hbuf,
    const float* __restrict__ out_w, const float* __restrict__ out_b,
    float* __restrict__ out)
{
    __shared__ float red[256];
    int b = blockIdx.x;
    float p = 0.0f;
    for (int e = threadIdx.x; e < HH; e += 256) {
        float cv = conv_b[e];
#pragma unroll
        for (int zz = 0; zz < 2; ++zz)
            cv += convp[(size_t)zz * cstride + (size_t)b * HH + e];
        p += (theme[(size_t)b * HH + e] * cv + hbuf[(size_t)b * HH + e]) * out_w[e];
    }
    red[threadIdx.x] = p;
    __syncthreads();
    for (int s = 128; s > 0; s >>= 1) {
        if (threadIdx.x < s) red[threadIdx.x] += red[threadIdx.x + s];
        __syncthreads();
    }
    if (threadIdx.x == 0) out[b] = sigf(red[0] + out_b[0]);
}

// ---------------------------------------------------------------------------
extern "C" void kernel_launch(void* const* d_in, const int* in_sizes, int n_in,
                              void* d_out, int out_size, void* d_ws, size_t ws_size,
                              hipStream_t stream)
{
    const float* x       = (const float*)d_in[0];
    const float* timep   = (const float*)d_in[1];
    const float* kw      = (const float*)d_in[2];
    const float* kb      = (const float*)d_in[3];
    const float* rw      = (const float*)d_in[4];
    const float* rb      = (const float*)d_in[5];
    const float* scale_w = (const float*)d_in[6];
    const float* scale_b = (const float*)d_in[7];
    const float* resc_w  = (const float*)d_in[8];
    const float* resc_b  = (const float*)d_in[9];
    const float* conv_w  = (const float*)d_in[10];
    const float* conv_b  = (const float*)d_in[11];
    const float* out_w   = (const float*)d_in[12];
    const float* out_b   = (const float*)d_in[13];

    float* outp  = (float*)d_out;
    float* distp = outp + BATCH;

    char* cur = (char*)d_ws;
    auto carve = [&](size_t bytes) {
        char* p = cur;
        cur += (bytes + 255) & ~(size_t)255;
        return (void*)p;
    };
    __hip_bfloat16* W4     = (__hip_bfloat16*)carve((size_t)G4 * KPACK * 2);
    __hip_bfloat16* Wm     = (__hip_bfloat16*)carve((size_t)16 * KPACK * 2);
    __hip_bfloat16* Ab0    = (__hip_bfloat16*)carve((size_t)BATCH * KPACK * 2);
    __hip_bfloat16* Ab1    = (__hip_bfloat16*)carve((size_t)BATCH * KPACK * 2);
    __hip_bfloat16* Lhb    = (__hip_bfloat16*)carve((size_t)BATCH * HH * KCONV * 2);
    __hip_bfloat16* convwb = (__hip_bfloat16*)carve((size_t)HH * HH * KCONV * 2);
    float* bias4 = (float*)carve(G4 * 4);
    float* tco4  = (float*)carve(G4 * 4);
    float* mbias = (float*)carve(64);
    float* mtco  = (float*)carve(64);
    float* cbuf  = (float*)carve((size_t)BATCH * HH * 4);
    float* hwin  = (float*)carve((size_t)KCONV * BATCH * HH * 4);
    float* ld    = (float*)carve((size_t)BATCH * KCONV * 4);
    float* mh    = (float*)carve((size_t)BATCH * HH * 4);
    float* s1    = (float*)carve((size_t)BATCH * CHW * 4);
    float* theme = (float*)carve((size_t)BATCH * HH * 4);
    float* convp = (float*)carve(2 * (size_t)BATCH * HH * 4);

    hipMemsetAsync(cbuf, 0, (size_t)BATCH * HH * sizeof(float), stream);
    prep_w4<<<G4, 256, 0, stream>>>(kw, kb, rw, rb, W4, bias4, tco4);
    prep_wm<<<16, 256, 0, stream>>>(kw, kb, rw, rb, Wm, mbias, mtco);
    cvt_kernel<<<(HH * HH * KCONV + 255) / 256, 256, 0, stream>>>(
        conv_w, convwb, HH * HH * KCONV);
    init_ab<<<BATCH, 256, 0, stream>>>(x, Ab0);

    for (int t = 0; t < TT; ++t) {
        const __hip_bfloat16* AbR = (t & 1) ? Ab1 : Ab0;
        __hip_bfloat16*       AbW = (t & 1) ? Ab0 : Ab1;
        step_kernel<<<256, 512, 0, stream>>>(
            AbR, AbW, x, timep, W4, Wm, bias4, tco4, mbias, mtco,
            cbuf, hwin, distp, t);
    }

    window_kernel<<<(BATCH + 255) / 256, 256, 0, stream>>>(distp, ld);
    localh_kernel<<<(BATCH * HH) / 256, 256, 0, stream>>>(hwin, ld, Lhb, mh);

    // conv einsum: [B,7680]bf16 x [768,7680]bf16^T, K-split x2
    gemm_mfma<2><<<16 * 6 * 2, 256, 0, stream>>>(
        Lhb, HH * KCONV, convwb, HH * KCONV, convp, HH, (size_t)BATCH * HH,
        HH * KCONV, 16, 6);
    // scale (relu): [B,768] x [128,768]^T
    gemm_nt<2><<<dim3(CHW / BN, BATCH / BM), 256, 0, stream>>>(
        mh, HH, scale_w, HH, scale_b, s1, CHW, BATCH, CHW, HH);
    // rescale (sigmoid): [B,128] x [768,128]^T
    gemm_nt<3><<<dim3(HH / BN, BATCH / BM), 256, 0, stream>>>(
        s1, CHW, resc_w, CHW, resc_b, theme, HH, BATCH, HH, CHW);

    out_kernel<<<BATCH, 256, 0, stream>>>(
        theme, convp, (size_t)BATCH * HH, conv_b,
        hwin + (size_t)((TT - 1) % KCONV) * BATCH * HH,   // h_last
        out_w, out_b, outp);
}